// Round 1
// baseline (1465.575 us; speedup 1.0000x reference)
//
#include <hip/hip_runtime.h>
#include <math.h>

namespace {

constexpr int kBatch = 32;
constexpr int kTok   = 512;
constexpr int kDim   = 768;
constexpr int kSlots = 64;
constexpr int kSteps = 4;
constexpr int kCls   = 8;
constexpr float kScale = 0.03608439182435161f;  // 1/sqrt(768)

// workspace offsets in floats
constexpr size_t QT_OFF  = 0;
constexpr size_t VT_OFF  = QT_OFF + (size_t)kBatch*kTok*kDim;
constexpr size_t M_OFF   = VT_OFF + (size_t)kBatch*kTok*kDim;
constexpr size_t KM_OFF  = M_OFF  + (size_t)kBatch*kSlots*kDim;
constexpr size_t G_OFF   = KM_OFF + (size_t)kBatch*kSlots*kDim;
constexpr size_t W_OFF   = G_OFF  + (size_t)kBatch*kSlots*kDim;
constexpr size_t VAL_OFF = W_OFF  + (size_t)kBatch*kTok*kSlots;

__device__ __forceinline__ float clipf(float x, float c) { return fminf(fmaxf(x, -c), c); }

// ---- M init: broadcast mem_init to all batches --------------------------------
__global__ __launch_bounds__(256) void k_minit(const float* __restrict__ mi, float* __restrict__ M) {
  int i = blockIdx.x * 256 + threadIdx.x;           // float4 index
  constexpr int per = kSlots * kDim / 4;            // 12288
  float4 v = reinterpret_cast<const float4*>(mi)[i % per];
  reinterpret_cast<float4*>(M)[i] = v;
}

// ---- valid[b] = sum of mask ---------------------------------------------------
__global__ __launch_bounds__(256) void k_valid(const int* __restrict__ mask, float* __restrict__ vf) {
  __shared__ float red[256];
  const int b = blockIdx.x, tid = threadIdx.x;
  float c = 0.f;
  for (int t = tid; t < kTok; t += 256) c += (mask[b*kTok + t] > 0) ? 1.f : 0.f;
  red[tid] = c; __syncthreads();
  for (int off = 128; off > 0; off >>= 1) { if (tid < off) red[tid] += red[tid+off]; __syncthreads(); }
  if (tid == 0) vf[b] = red[0];
}

// ---- Qt = x@Wq, Vt = x@Wv with x gathered on the fly --------------------------
// grid: (16384/64, 768/64), 256 thr, 64x64x16 tile, 4x4 per thread, dual output
__global__ __launch_bounds__(256) void k_embed_qv(
    const int* __restrict__ ids, const float* __restrict__ tok, const float* __restrict__ pos,
    const float* __restrict__ Wq, const float* __restrict__ Wv,
    float* __restrict__ Qt, float* __restrict__ Vt)
{
  __shared__ float As[64][17];
  __shared__ float Bq[16][64];
  __shared__ float Bv[16][64];
  __shared__ int   rid[64];
  const int tid = threadIdx.x;
  const int m0 = blockIdx.x * 64, n0 = blockIdx.y * 64;
  if (tid < 64) rid[tid] = ids[m0 + tid];
  const int arow = tid >> 2, akb = (tid & 3) << 2;
  const int brow = tid >> 4, bcol = (tid & 15) << 2;
  const int ty = tid >> 4, tx = tid & 15;
  const int posrow = (m0 + arow) & (kTok - 1);
  float aq[4][4] = {{0.f}}, av[4][4] = {{0.f}};
  __syncthreads();
  const float* tokrow = tok + (size_t)rid[arow] * kDim;
  const float* posptr = pos + (size_t)posrow * kDim;
  for (int k0 = 0; k0 < kDim; k0 += 16) {
    float4 tv = *reinterpret_cast<const float4*>(tokrow + k0 + akb);
    float4 pv = *reinterpret_cast<const float4*>(posptr + k0 + akb);
    As[arow][akb+0] = tv.x + pv.x; As[arow][akb+1] = tv.y + pv.y;
    As[arow][akb+2] = tv.z + pv.z; As[arow][akb+3] = tv.w + pv.w;
    *reinterpret_cast<float4*>(&Bq[brow][bcol]) =
        *reinterpret_cast<const float4*>(Wq + (size_t)(k0+brow)*kDim + n0 + bcol);
    *reinterpret_cast<float4*>(&Bv[brow][bcol]) =
        *reinterpret_cast<const float4*>(Wv + (size_t)(k0+brow)*kDim + n0 + bcol);
    __syncthreads();
    #pragma unroll
    for (int kk = 0; kk < 16; ++kk) {
      float a[4];
      #pragma unroll
      for (int i = 0; i < 4; ++i) a[i] = As[ty*4+i][kk];
      float4 q4 = *reinterpret_cast<const float4*>(&Bq[kk][tx*4]);
      float4 v4 = *reinterpret_cast<const float4*>(&Bv[kk][tx*4]);
      float qb[4] = {q4.x, q4.y, q4.z, q4.w};
      float vb[4] = {v4.x, v4.y, v4.z, v4.w};
      #pragma unroll
      for (int i = 0; i < 4; ++i)
        #pragma unroll
        for (int j = 0; j < 4; ++j) { aq[i][j] += a[i]*qb[j]; av[i][j] += a[i]*vb[j]; }
    }
    __syncthreads();
  }
  #pragma unroll
  for (int i = 0; i < 4; ++i) {
    size_t ro = (size_t)(m0 + ty*4 + i) * kDim + n0 + tx*4;
    *reinterpret_cast<float4*>(Qt + ro) = make_float4(aq[i][0], aq[i][1], aq[i][2], aq[i][3]);
    *reinterpret_cast<float4*>(Vt + ro) = make_float4(av[i][0], av[i][1], av[i][2], av[i][3]);
  }
}

// ---- Km = M@Wk (+ g = sigmoid(M@gate_W + gb)) ---------------------------------
// A = M flattened (2048,768). grid: (2048/64, 768/64)
template <bool DO_GATE>
__global__ __launch_bounds__(256) void k_mgate(
    const float* __restrict__ M, const float* __restrict__ Wk,
    const float* __restrict__ gW, const float* __restrict__ gb,
    float* __restrict__ Km, float* __restrict__ G)
{
  __shared__ float As[64][17];
  __shared__ float Bk[16][64];
  __shared__ float Bg[16][64];
  const int tid = threadIdx.x;
  const int m0 = blockIdx.x * 64, n0 = blockIdx.y * 64;
  const int arow = tid >> 2, akb = (tid & 3) << 2;
  const int brow = tid >> 4, bcol = (tid & 15) << 2;
  const int ty = tid >> 4, tx = tid & 15;
  float ak[4][4] = {{0.f}}, ag[4][4] = {{0.f}};
  const float* Arow = M + (size_t)(m0 + arow) * kDim;
  for (int k0 = 0; k0 < kDim; k0 += 16) {
    float4 a4 = *reinterpret_cast<const float4*>(Arow + k0 + akb);
    As[arow][akb+0] = a4.x; As[arow][akb+1] = a4.y; As[arow][akb+2] = a4.z; As[arow][akb+3] = a4.w;
    *reinterpret_cast<float4*>(&Bk[brow][bcol]) =
        *reinterpret_cast<const float4*>(Wk + (size_t)(k0+brow)*kDim + n0 + bcol);
    if (DO_GATE)
      *reinterpret_cast<float4*>(&Bg[brow][bcol]) =
          *reinterpret_cast<const float4*>(gW + (size_t)(k0+brow)*kDim + n0 + bcol);
    __syncthreads();
    #pragma unroll
    for (int kk = 0; kk < 16; ++kk) {
      float a[4];
      #pragma unroll
      for (int i = 0; i < 4; ++i) a[i] = As[ty*4+i][kk];
      float4 k4 = *reinterpret_cast<const float4*>(&Bk[kk][tx*4]);
      float kb[4] = {k4.x, k4.y, k4.z, k4.w};
      float gbv[4];
      if (DO_GATE) {
        float4 g4 = *reinterpret_cast<const float4*>(&Bg[kk][tx*4]);
        gbv[0]=g4.x; gbv[1]=g4.y; gbv[2]=g4.z; gbv[3]=g4.w;
      }
      #pragma unroll
      for (int i = 0; i < 4; ++i)
        #pragma unroll
        for (int j = 0; j < 4; ++j) {
          ak[i][j] += a[i]*kb[j];
          if (DO_GATE) ag[i][j] += a[i]*gbv[j];
        }
    }
    __syncthreads();
  }
  #pragma unroll
  for (int i = 0; i < 4; ++i) {
    size_t ro = (size_t)(m0 + ty*4 + i) * kDim + n0 + tx*4;
    *reinterpret_cast<float4*>(Km + ro) = make_float4(ak[i][0], ak[i][1], ak[i][2], ak[i][3]);
    if (DO_GATE) {
      float gv[4];
      #pragma unroll
      for (int j = 0; j < 4; ++j) {
        float z = ag[i][j] + gb[n0 + tx*4 + j];
        gv[j] = 1.f / (1.f + __expf(-z));
      }
      *reinterpret_cast<float4*>(G + ro) = make_float4(gv[0], gv[1], gv[2], gv[3]);
    }
  }
}

// ---- scores = clip(Qt@Km^T * scale) -> masked softmax -> W --------------------
// grid: (512/64, 32). Block covers 64 t-rows x all 64 slots, K=768.
__global__ __launch_bounds__(256) void k_scores(
    const float* __restrict__ Qt, const float* __restrict__ Km,
    const int* __restrict__ mask, const float* __restrict__ vf,
    float* __restrict__ W)
{
  __shared__ float As[64][17];
  __shared__ float Bs[64][17];
  __shared__ float sc[64][65];
  __shared__ float fac[64];
  const int b = blockIdx.y, t0 = blockIdx.x * 64, tid = threadIdx.x;
  const int arow = tid >> 2, akb = (tid & 3) << 2;
  const int ty = tid >> 4, tx = tid & 15;
  float acc[4][4] = {{0.f}};
  const float* Abase = Qt + ((size_t)(b*kTok + t0) + arow) * kDim;
  const float* Bbase = Km + ((size_t)(b*kSlots) + arow) * kDim;
  for (int k0 = 0; k0 < kDim; k0 += 16) {
    float4 a4 = *reinterpret_cast<const float4*>(Abase + k0 + akb);
    As[arow][akb+0] = a4.x; As[arow][akb+1] = a4.y; As[arow][akb+2] = a4.z; As[arow][akb+3] = a4.w;
    float4 b4 = *reinterpret_cast<const float4*>(Bbase + k0 + akb);
    Bs[arow][akb+0] = b4.x; Bs[arow][akb+1] = b4.y; Bs[arow][akb+2] = b4.z; Bs[arow][akb+3] = b4.w;
    __syncthreads();
    #pragma unroll
    for (int kk = 0; kk < 16; ++kk) {
      float a[4], bb[4];
      #pragma unroll
      for (int i = 0; i < 4; ++i) a[i]  = As[ty*4+i][kk];
      #pragma unroll
      for (int j = 0; j < 4; ++j) bb[j] = Bs[tx*4+j][kk];
      #pragma unroll
      for (int i = 0; i < 4; ++i)
        #pragma unroll
        for (int j = 0; j < 4; ++j) acc[i][j] += a[i]*bb[j];
    }
    __syncthreads();
  }
  #pragma unroll
  for (int i = 0; i < 4; ++i)
    #pragma unroll
    for (int j = 0; j < 4; ++j)
      sc[ty*4+i][tx*4+j] = clipf(acc[i][j] * kScale, 20.f);
  __syncthreads();
  if (tid < 64) {
    const int r = tid;
    float mx = -1e30f;
    for (int s = 0; s < kSlots; ++s) mx = fmaxf(mx, sc[r][s]);
    float sum = 0.f;
    for (int s = 0; s < kSlots; ++s) { float e = __expf(sc[r][s] - mx); sc[r][s] = e; sum += e; }
    const bool tokkeep = mask[b*kTok + t0 + r] > 0;
    const bool keep = tokkeep || (vf[b] == 0.f);
    fac[r] = keep ? (1.f / sum) : 0.f;
  }
  __syncthreads();
  float* Wb = W + (size_t)(b*kTok + t0) * kSlots;
  for (int idx = tid; idx < 64*64; idx += 256) {
    int r = idx >> 6, s = idx & 63;
    Wb[(size_t)r*kSlots + s] = sc[r][s] * fac[r];
  }
}

// ---- write = W^T @ Vt fused with M update -------------------------------------
// grid: (768/64, 32). Output rows = 64 slots (full), cols = 64 of 768, K = 512.
__global__ __launch_bounds__(256) void k_write_update(
    const float* __restrict__ W, const float* __restrict__ Vt,
    const float* __restrict__ G, float* __restrict__ M)
{
  __shared__ float As[16][64];   // [t][s]
  __shared__ float Bs[16][64];   // [t][d]
  const int b = blockIdx.y, n0 = blockIdx.x * 64, tid = threadIdx.x;
  const int trow = tid >> 4, c4 = (tid & 15) << 2;
  const int ty = tid >> 4, tx = tid & 15;
  float acc[4][4] = {{0.f}};
  const float* Wb = W  + (size_t)(b*kTok) * kSlots;
  const float* Vb = Vt + (size_t)(b*kTok) * kDim;
  for (int k0 = 0; k0 < kTok; k0 += 16) {
    *reinterpret_cast<float4*>(&As[trow][c4]) =
        *reinterpret_cast<const float4*>(Wb + (size_t)(k0+trow)*kSlots + c4);
    *reinterpret_cast<float4*>(&Bs[trow][c4]) =
        *reinterpret_cast<const float4*>(Vb + (size_t)(k0+trow)*kDim + n0 + c4);
    __syncthreads();
    #pragma unroll
    for (int kk = 0; kk < 16; ++kk) {
      float4 a4 = *reinterpret_cast<const float4*>(&As[kk][ty*4]);
      float4 b4 = *reinterpret_cast<const float4*>(&Bs[kk][tx*4]);
      float a[4] = {a4.x, a4.y, a4.z, a4.w};
      float bb[4] = {b4.x, b4.y, b4.z, b4.w};
      #pragma unroll
      for (int i = 0; i < 4; ++i)
        #pragma unroll
        for (int j = 0; j < 4; ++j) acc[i][j] += a[i]*bb[j];
    }
    __syncthreads();
  }
  #pragma unroll
  for (int i = 0; i < 4; ++i) {
    const int srow = ty*4 + i;
    size_t off = (size_t)(b*kSlots + srow) * kDim + n0 + tx*4;
    float4 mo = *reinterpret_cast<const float4*>(M + off);
    float4 gv = *reinterpret_cast<const float4*>(G + off);
    float4 r;
    r.x = clipf(0.9f*mo.x + 0.1f*gv.x*acc[i][0], 50.f);
    r.y = clipf(0.9f*mo.y + 0.1f*gv.y*acc[i][1], 50.f);
    r.z = clipf(0.9f*mo.z + 0.1f*gv.z*acc[i][2], 50.f);
    r.w = clipf(0.9f*mo.w + 0.1f*gv.w*acc[i][3], 50.f);
    *reinterpret_cast<float4*>(M + off) = r;
  }
}

// ---- pooled = (sum_t m*W) @ M / cnt -> LN -> logits ---------------------------
__global__ __launch_bounds__(256) void k_final(
    const float* __restrict__ W, const float* __restrict__ M,
    const int* __restrict__ mask, const float* __restrict__ vf,
    const float* __restrict__ lng, const float* __restrict__ lnb,
    const float* __restrict__ clsW, const float* __restrict__ clsb,
    float* __restrict__ out)
{
  __shared__ float red[256];
  __shared__ float wsum[kSlots];
  __shared__ float pooled[kDim];
  __shared__ float sh_mu, sh_var;
  const int b = blockIdx.x, tid = threadIdx.x;

  {
    const int s = tid & 63, chunk = tid >> 6;
    float p = 0.f;
    for (int t = chunk*128; t < chunk*128 + 128; ++t)
      if (mask[b*kTok + t] > 0) p += W[((size_t)(b*kTok + t))*kSlots + s];
    red[tid] = p;
  }
  __syncthreads();
  if (tid < 64) wsum[tid] = red[tid] + red[tid+64] + red[tid+128] + red[tid+192];
  __syncthreads();

  const float denom = fmaxf(vf[b], 1.f);
  for (int d = tid; d < kDim; d += 256) {
    float acc = 0.f;
    const float* Mb = M + (size_t)(b*kSlots)*kDim + d;
    #pragma unroll 4
    for (int s = 0; s < kSlots; ++s) acc += wsum[s] * Mb[(size_t)s*kDim];
    pooled[d] = acc / denom;
  }
  __syncthreads();

  float lp = 0.f;
  for (int d = tid; d < kDim; d += 256) lp += pooled[d];
  red[tid] = lp; __syncthreads();
  for (int off = 128; off > 0; off >>= 1) { if (tid < off) red[tid] += red[tid+off]; __syncthreads(); }
  if (tid == 0) sh_mu = red[0] / kDim;
  __syncthreads();
  const float mu = sh_mu;
  float lv = 0.f;
  for (int d = tid; d < kDim; d += 256) { float z = pooled[d] - mu; lv += z*z; }
  red[tid] = lv; __syncthreads();
  for (int off = 128; off > 0; off >>= 1) { if (tid < off) red[tid] += red[tid+off]; __syncthreads(); }
  if (tid == 0) sh_var = red[0] / kDim;
  __syncthreads();
  const float inv = rsqrtf(sh_var + 1e-5f);
  for (int d = tid; d < kDim; d += 256)
    pooled[d] = (pooled[d] - mu) * inv * lng[d] + lnb[d];
  __syncthreads();

  {
    const int c = tid & 7, dg = tid >> 3;
    float part = 0.f;
    for (int d = dg; d < kDim; d += 32) part += pooled[d] * clsW[(size_t)d*kCls + c];
    red[tid] = part;
  }
  __syncthreads();
  if (tid < 8) {
    float s = clsb[tid];
    #pragma unroll
    for (int dg = 0; dg < 32; ++dg) s += red[dg*8 + tid];
    if (!isfinite(s)) s = 0.f;
    out[b*kCls + tid] = s;
  }
}

}  // namespace

extern "C" void kernel_launch(void* const* d_in, const int* in_sizes, int n_in,
                              void* d_out, int out_size, void* d_ws, size_t ws_size,
                              hipStream_t stream)
{
  const int*   ids = (const int*)  d_in[0];
  const int*   msk = (const int*)  d_in[1];
  const float* tok = (const float*)d_in[2];
  const float* pos = (const float*)d_in[3];
  const float* Wq  = (const float*)d_in[4];
  const float* Wk  = (const float*)d_in[5];
  const float* Wv  = (const float*)d_in[6];
  const float* gW  = (const float*)d_in[7];
  const float* gb  = (const float*)d_in[8];
  const float* lng = (const float*)d_in[9];
  const float* lnb = (const float*)d_in[10];
  const float* cW  = (const float*)d_in[11];
  const float* cb  = (const float*)d_in[12];
  const float* mi  = (const float*)d_in[13];
  float* out = (float*)d_out;
  float* ws  = (float*)d_ws;

  float* Qt = ws + QT_OFF;
  float* Vt = ws + VT_OFF;
  float* M  = ws + M_OFF;
  float* Km = ws + KM_OFF;
  float* G  = ws + G_OFF;
  float* Wb = ws + W_OFF;
  float* vf = ws + VAL_OFF;

  k_minit<<<dim3((kBatch*kSlots*kDim/4)/256), 256, 0, stream>>>(mi, M);
  k_valid<<<dim3(kBatch), 256, 0, stream>>>(msk, vf);
  k_embed_qv<<<dim3(kBatch*kTok/64, kDim/64), 256, 0, stream>>>(ids, tok, pos, Wq, Wv, Qt, Vt);
  for (int it = 0; it < kSteps; ++it) {
    k_mgate<true><<<dim3(kBatch*kSlots/64, kDim/64), 256, 0, stream>>>(M, Wk, gW, gb, Km, G);
    k_scores<<<dim3(kTok/64, kBatch), 256, 0, stream>>>(Qt, Km, msk, vf, Wb);
    k_write_update<<<dim3(kDim/64, kBatch), 256, 0, stream>>>(Wb, Vt, G, M);
  }
  k_mgate<false><<<dim3(kBatch*kSlots/64, kDim/64), 256, 0, stream>>>(M, Wk, gW, gb, Km, G);
  k_scores<<<dim3(kTok/64, kBatch), 256, 0, stream>>>(Qt, Km, msk, vf, Wb);
  k_final<<<dim3(kBatch), 256, 0, stream>>>(Wb, M, msk, vf, lng, lnb, cW, cb, out);

  (void)in_sizes; (void)n_in; (void)out_size; (void)ws_size;
}

// Round 4
// 737.914 us; speedup vs baseline: 1.9861x; 1.9861x over previous
//
#include <hip/hip_runtime.h>
#include <math.h>

namespace {

constexpr int kBatch = 32;
constexpr int kTok   = 512;
constexpr int kDim   = 768;
constexpr int kSlots = 64;
constexpr int kSteps = 4;
constexpr int kCls   = 8;
constexpr float kScale = 0.03608439182435161f;  // 1/sqrt(768)

typedef __attribute__((ext_vector_type(4))) float f32x4;
typedef __attribute__((ext_vector_type(8))) short bf16x8;      // 8 bf16 (4 VGPRs)
typedef __attribute__((ext_vector_type(8))) unsigned short u16x8;
typedef __attribute__((ext_vector_type(4))) unsigned short u16x4;

__device__ __forceinline__ float clipf(float x, float c) { return fminf(fmaxf(x, -c), c); }
__device__ __forceinline__ unsigned short f2bf(float f) {
  unsigned u = __float_as_uint(f);
  return (unsigned short)((u + 0x7fffu + ((u >> 16) & 1u)) >> 16);  // RNE
}
__device__ __forceinline__ float bf2f(unsigned short h) {
  return __uint_as_float(((unsigned)h) << 16);
}

// ---------------- weight transpose + cvt: W[768][768] f32 -> WT[768][768] bf16 --
__global__ __launch_bounds__(256) void k_prep(
    const float* __restrict__ Wq, const float* __restrict__ Wk,
    const float* __restrict__ Wv, const float* __restrict__ gW,
    unsigned short* __restrict__ WqT, unsigned short* __restrict__ WkT,
    unsigned short* __restrict__ WvT, unsigned short* __restrict__ gWT)
{
  __shared__ float tile[32][33];
  const int mat = blockIdx.z;
  const float* src = (mat == 0) ? Wq : (mat == 1) ? Wk : (mat == 2) ? Wv : gW;
  unsigned short* dst = (mat == 0) ? WqT : (mat == 1) ? WkT : (mat == 2) ? WvT : gWT;
  const int tx = threadIdx.x & 31, ty = threadIdx.x >> 5;
  const int r0 = blockIdx.y * 32, c0 = blockIdx.x * 32;
  #pragma unroll
  for (int q = 0; q < 4; ++q)
    tile[ty + 8*q][tx] = src[(size_t)(r0 + ty + 8*q) * kDim + c0 + tx];
  __syncthreads();
  #pragma unroll
  for (int q = 0; q < 4; ++q)
    dst[(size_t)(c0 + ty + 8*q) * kDim + r0 + tx] = f2bf(tile[tx][ty + 8*q]);
}

// ---------------- M init -------------------------------------------------------
__global__ __launch_bounds__(256) void k_minit(const float* __restrict__ mi, float* __restrict__ M) {
  int i = blockIdx.x * 256 + threadIdx.x;
  constexpr int per = kSlots * kDim / 4;
  float4 v = reinterpret_cast<const float4*>(mi)[i % per];
  reinterpret_cast<float4*>(M)[i] = v;
}

// ---------------- valid[b] -----------------------------------------------------
__global__ __launch_bounds__(256) void k_valid(const int* __restrict__ mask, float* __restrict__ vf) {
  __shared__ float red[256];
  const int b = blockIdx.x, tid = threadIdx.x;
  float c = 0.f;
  for (int t = tid; t < kTok; t += 256) c += (mask[b*kTok + t] > 0) ? 1.f : 0.f;
  red[tid] = c; __syncthreads();
  for (int off = 128; off > 0; off >>= 1) { if (tid < off) red[tid] += red[tid+off]; __syncthreads(); }
  if (tid == 0) vf[b] = red[0];
}

// ---------------- Qt = x@Wq, VtT = (x@Wv)^T  (MFMA, dual B) --------------------
// grid (16384/128, 768/128), 256 thr = 4 waves in 2x2, each wave 64x64 per output
__global__ __launch_bounds__(256) void k_embed_qv(
    const int* __restrict__ ids, const float* __restrict__ tok, const float* __restrict__ pos,
    const unsigned short* __restrict__ WqT, const unsigned short* __restrict__ WvT,
    unsigned short* __restrict__ Qt, unsigned short* __restrict__ VtT)
{
  __shared__ unsigned short As[128][32];
  __shared__ unsigned short Bq[128][32];
  __shared__ unsigned short Bv[128][32];
  __shared__ int rid[128];
  const int tid = threadIdx.x;
  const int m0 = blockIdx.x * 128, n0 = blockIdx.y * 128;
  if (tid < 128) rid[tid] = ids[m0 + tid];
  const int wave = tid >> 6, lane = tid & 63;
  const int wr = wave >> 1, wc = wave & 1;
  const int ar = tid >> 1, ac = (tid & 1) << 4;   // staging: row, 16-col group
  f32x4 accq[4][4], accv[4][4];
  #pragma unroll
  for (int i = 0; i < 4; ++i)
    #pragma unroll
    for (int j = 0; j < 4; ++j) { accq[i][j] = (f32x4)(0.f); accv[i][j] = (f32x4)(0.f); }
  __syncthreads();
  const float* tokrow = tok + (size_t)rid[ar] * kDim;
  const float* posrow = pos + (size_t)((m0 + ar) & (kTok - 1)) * kDim;
  const unsigned short* bqrow = WqT + (size_t)(n0 + ar) * kDim;
  const unsigned short* bvrow = WvT + (size_t)(n0 + ar) * kDim;
  const int fr = lane & 15, kg = (lane >> 4) << 3;

  for (int k0 = 0; k0 < kDim; k0 += 32) {
    unsigned short av[16];
    #pragma unroll
    for (int q = 0; q < 4; ++q) {
      float4 tv = *reinterpret_cast<const float4*>(tokrow + k0 + ac + 4*q);
      float4 pv = *reinterpret_cast<const float4*>(posrow + k0 + ac + 4*q);
      av[4*q+0] = f2bf(tv.x + pv.x); av[4*q+1] = f2bf(tv.y + pv.y);
      av[4*q+2] = f2bf(tv.z + pv.z); av[4*q+3] = f2bf(tv.w + pv.w);
    }
    *reinterpret_cast<u16x8*>(&As[ar][ac])     = *reinterpret_cast<u16x8*>(&av[0]);
    *reinterpret_cast<u16x8*>(&As[ar][ac + 8]) = *reinterpret_cast<u16x8*>(&av[8]);
    *reinterpret_cast<u16x8*>(&Bq[ar][ac])     = *reinterpret_cast<const u16x8*>(bqrow + k0 + ac);
    *reinterpret_cast<u16x8*>(&Bq[ar][ac + 8]) = *reinterpret_cast<const u16x8*>(bqrow + k0 + ac + 8);
    *reinterpret_cast<u16x8*>(&Bv[ar][ac])     = *reinterpret_cast<const u16x8*>(bvrow + k0 + ac);
    *reinterpret_cast<u16x8*>(&Bv[ar][ac + 8]) = *reinterpret_cast<const u16x8*>(bvrow + k0 + ac + 8);
    __syncthreads();
    bf16x8 a[4], bq[4], bv[4];
    #pragma unroll
    for (int mt = 0; mt < 4; ++mt) a[mt] = *reinterpret_cast<const bf16x8*>(&As[wr*64 + mt*16 + fr][kg]);
    #pragma unroll
    for (int nt = 0; nt < 4; ++nt) {
      bq[nt] = *reinterpret_cast<const bf16x8*>(&Bq[wc*64 + nt*16 + fr][kg]);
      bv[nt] = *reinterpret_cast<const bf16x8*>(&Bv[wc*64 + nt*16 + fr][kg]);
    }
    #pragma unroll
    for (int mt = 0; mt < 4; ++mt)
      #pragma unroll
      for (int nt = 0; nt < 4; ++nt) {
        accq[mt][nt] = __builtin_amdgcn_mfma_f32_16x16x32_bf16(a[mt], bq[nt], accq[mt][nt], 0, 0, 0);
        accv[mt][nt] = __builtin_amdgcn_mfma_f32_16x16x32_bf16(a[mt], bv[nt], accv[mt][nt], 0, 0, 0);
      }
    __syncthreads();
  }
  // Qt[t][d] bf16 (scattered 2B); VtT[b][d][t] bf16 (8B packed along t)
  const int b = m0 >> 9;
  unsigned short* vb = VtT + (size_t)b * kDim * kTok;
  #pragma unroll
  for (int mt = 0; mt < 4; ++mt) {
    const int trow = m0 + wr*64 + mt*16 + ((lane >> 4) << 2);
    const int tloc = (trow & (kTok - 1));
    #pragma unroll
    for (int nt = 0; nt < 4; ++nt) {
      const int dcol = n0 + wc*64 + nt*16 + (lane & 15);
      u16x4 pk;
      #pragma unroll
      for (int r = 0; r < 4; ++r) {
        Qt[(size_t)(trow + r) * kDim + dcol] = f2bf(accq[mt][nt][r]);
        pk[r] = f2bf(accv[mt][nt][r]);
      }
      *reinterpret_cast<u16x4*>(vb + (size_t)dcol * kTok + tloc) = pk;
    }
  }
}

// ---------------- Km = M@Wk (+ G = sigmoid(M@gate_W + gb)) (MFMA, dual B) ------
// grid (2048/128, 768/128)
template <bool DO_GATE>
__global__ __launch_bounds__(256) void k_mgate(
    const float* __restrict__ M, const unsigned short* __restrict__ WkT,
    const unsigned short* __restrict__ gWT, const float* __restrict__ gb,
    unsigned short* __restrict__ Km, float* __restrict__ G)
{
  __shared__ unsigned short As[128][32];
  __shared__ unsigned short Bk[128][32];
  __shared__ unsigned short Bg[128][32];
  const int tid = threadIdx.x;
  const int m0 = blockIdx.x * 128, n0 = blockIdx.y * 128;
  const int wave = tid >> 6, lane = tid & 63;
  const int wr = wave >> 1, wc = wave & 1;
  const int ar = tid >> 1, ac = (tid & 1) << 4;
  f32x4 acck[4][4], accg[4][4];
  #pragma unroll
  for (int i = 0; i < 4; ++i)
    #pragma unroll
    for (int j = 0; j < 4; ++j) { acck[i][j] = (f32x4)(0.f); accg[i][j] = (f32x4)(0.f); }
  const float* arow = M + (size_t)(m0 + ar) * kDim;
  const unsigned short* bkrow = WkT + (size_t)(n0 + ar) * kDim;
  const unsigned short* bgrow = gWT + (size_t)(n0 + ar) * kDim;
  const int fr = lane & 15, kg = (lane >> 4) << 3;

  for (int k0 = 0; k0 < kDim; k0 += 32) {
    unsigned short av[16];
    #pragma unroll
    for (int q = 0; q < 4; ++q) {
      float4 v = *reinterpret_cast<const float4*>(arow + k0 + ac + 4*q);
      av[4*q+0] = f2bf(v.x); av[4*q+1] = f2bf(v.y); av[4*q+2] = f2bf(v.z); av[4*q+3] = f2bf(v.w);
    }
    *reinterpret_cast<u16x8*>(&As[ar][ac])     = *reinterpret_cast<u16x8*>(&av[0]);
    *reinterpret_cast<u16x8*>(&As[ar][ac + 8]) = *reinterpret_cast<u16x8*>(&av[8]);
    *reinterpret_cast<u16x8*>(&Bk[ar][ac])     = *reinterpret_cast<const u16x8*>(bkrow + k0 + ac);
    *reinterpret_cast<u16x8*>(&Bk[ar][ac + 8]) = *reinterpret_cast<const u16x8*>(bkrow + k0 + ac + 8);
    if (DO_GATE) {
      *reinterpret_cast<u16x8*>(&Bg[ar][ac])     = *reinterpret_cast<const u16x8*>(bgrow + k0 + ac);
      *reinterpret_cast<u16x8*>(&Bg[ar][ac + 8]) = *reinterpret_cast<const u16x8*>(bgrow + k0 + ac + 8);
    }
    __syncthreads();
    bf16x8 a[4], bk[4], bg[4];
    #pragma unroll
    for (int mt = 0; mt < 4; ++mt) a[mt] = *reinterpret_cast<const bf16x8*>(&As[wr*64 + mt*16 + fr][kg]);
    #pragma unroll
    for (int nt = 0; nt < 4; ++nt) {
      bk[nt] = *reinterpret_cast<const bf16x8*>(&Bk[wc*64 + nt*16 + fr][kg]);
      if (DO_GATE) bg[nt] = *reinterpret_cast<const bf16x8*>(&Bg[wc*64 + nt*16 + fr][kg]);
    }
    #pragma unroll
    for (int mt = 0; mt < 4; ++mt)
      #pragma unroll
      for (int nt = 0; nt < 4; ++nt) {
        acck[mt][nt] = __builtin_amdgcn_mfma_f32_16x16x32_bf16(a[mt], bk[nt], acck[mt][nt], 0, 0, 0);
        if (DO_GATE) accg[mt][nt] = __builtin_amdgcn_mfma_f32_16x16x32_bf16(a[mt], bg[nt], accg[mt][nt], 0, 0, 0);
      }
    __syncthreads();
  }
  #pragma unroll
  for (int mt = 0; mt < 4; ++mt) {
    const int row = m0 + wr*64 + mt*16 + ((lane >> 4) << 2);
    #pragma unroll
    for (int nt = 0; nt < 4; ++nt) {
      const int col = n0 + wc*64 + nt*16 + (lane & 15);
      #pragma unroll
      for (int r = 0; r < 4; ++r) {
        Km[(size_t)(row + r) * kDim + col] = f2bf(acck[mt][nt][r]);
        if (DO_GATE) {
          float z = accg[mt][nt][r] + gb[col];
          G[(size_t)(row + r) * kDim + col] = 1.f / (1.f + __expf(-z));
        }
      }
    }
  }
}

// ---------------- scores -> masked softmax -> Wt[b][s][t] (MFMA) ---------------
// grid (512/128, 32). 4 waves, each 32 t-rows x 64 slots, K=768.
__global__ __launch_bounds__(256) void k_scores(
    const unsigned short* __restrict__ Qt, const unsigned short* __restrict__ Km,
    const int* __restrict__ mask, const float* __restrict__ vf,
    unsigned short* __restrict__ Wt)
{
  __shared__ unsigned short As[128][32];
  __shared__ unsigned short Bs[64][32];
  const int tid = threadIdx.x;
  const int b = blockIdx.y, t0 = blockIdx.x * 128;
  const int wave = tid >> 6, lane = tid & 63;
  const int ar = tid >> 1, ac = (tid & 1) << 4;
  const int br = tid >> 2, bc = (tid & 3) << 3;
  f32x4 acc[2][4];
  #pragma unroll
  for (int i = 0; i < 2; ++i)
    #pragma unroll
    for (int j = 0; j < 4; ++j) acc[i][j] = (f32x4)(0.f);
  const unsigned short* qrow = Qt + (size_t)(b*kTok + t0 + ar) * kDim;
  const unsigned short* krow = Km + (size_t)(b*kSlots + br) * kDim;
  const int fr = lane & 15, kg = (lane >> 4) << 3;

  for (int k0 = 0; k0 < kDim; k0 += 32) {
    *reinterpret_cast<u16x8*>(&As[ar][ac])     = *reinterpret_cast<const u16x8*>(qrow + k0 + ac);
    *reinterpret_cast<u16x8*>(&As[ar][ac + 8]) = *reinterpret_cast<const u16x8*>(qrow + k0 + ac + 8);
    *reinterpret_cast<u16x8*>(&Bs[br][bc])     = *reinterpret_cast<const u16x8*>(krow + k0 + bc);
    __syncthreads();
    bf16x8 a[2], bb[4];
    #pragma unroll
    for (int mt = 0; mt < 2; ++mt) a[mt] = *reinterpret_cast<const bf16x8*>(&As[wave*32 + mt*16 + fr][kg]);
    #pragma unroll
    for (int nt = 0; nt < 4; ++nt) bb[nt] = *reinterpret_cast<const bf16x8*>(&Bs[nt*16 + fr][kg]);
    #pragma unroll
    for (int mt = 0; mt < 2; ++mt)
      #pragma unroll
      for (int nt = 0; nt < 4; ++nt)
        acc[mt][nt] = __builtin_amdgcn_mfma_f32_16x16x32_bf16(a[mt], bb[nt], acc[mt][nt], 0, 0, 0);
    __syncthreads();
  }
  // clip + softmax over s (row = fixed t), mask factor
  #pragma unroll
  for (int mt = 0; mt < 2; ++mt)
    #pragma unroll
    for (int nt = 0; nt < 4; ++nt)
      #pragma unroll
      for (int r = 0; r < 4; ++r)
        acc[mt][nt][r] = clipf(acc[mt][nt][r] * kScale, 20.f);
  const float vfb = vf[b];
  float fac[2][4];
  #pragma unroll
  for (int mt = 0; mt < 2; ++mt) {
    #pragma unroll
    for (int r = 0; r < 4; ++r) {
      float mx = fmaxf(fmaxf(acc[mt][0][r], acc[mt][1][r]), fmaxf(acc[mt][2][r], acc[mt][3][r]));
      #pragma unroll
      for (int m = 1; m < 16; m <<= 1) mx = fmaxf(mx, __shfl_xor(mx, m, 64));
      float sum = 0.f;
      #pragma unroll
      for (int nt = 0; nt < 4; ++nt) { float e = __expf(acc[mt][nt][r] - mx); acc[mt][nt][r] = e; sum += e; }
      #pragma unroll
      for (int m = 1; m < 16; m <<= 1) sum += __shfl_xor(sum, m, 64);
      const int tloc = t0 + wave*32 + mt*16 + ((lane >> 4) << 2) + r;
      const bool keep = (mask[b*kTok + tloc] > 0) || (vfb == 0.f);
      fac[mt][r] = keep ? (1.f / sum) : 0.f;
    }
  }
  unsigned short* wb = Wt + (size_t)b * kSlots * kTok;
  #pragma unroll
  for (int mt = 0; mt < 2; ++mt) {
    const int tbase = t0 + wave*32 + mt*16 + ((lane >> 4) << 2);
    #pragma unroll
    for (int nt = 0; nt < 4; ++nt) {
      const int s = nt*16 + (lane & 15);
      u16x4 pk;
      #pragma unroll
      for (int r = 0; r < 4; ++r) pk[r] = f2bf(acc[mt][nt][r] * fac[mt][r]);
      *reinterpret_cast<u16x4*>(wb + (size_t)s * kTok + tbase) = pk;
    }
  }
}

// ---------------- write = Wt @ VtT^T fused with M update (MFMA) ----------------
// grid (768/256, 32). 4 waves, each 64 slots x 64 d, K=512.
__global__ __launch_bounds__(256) void k_write_update(
    const unsigned short* __restrict__ Wt, const unsigned short* __restrict__ VtT,
    const float* __restrict__ G, float* __restrict__ M)
{
  __shared__ unsigned short As[64][32];
  __shared__ unsigned short Bs[256][32];
  const int tid = threadIdx.x;
  const int b = blockIdx.y, n0 = blockIdx.x * 256;
  const int wave = tid >> 6, lane = tid & 63;
  const int ar = tid >> 2, ac = (tid & 3) << 3;
  f32x4 acc[4][4];
  #pragma unroll
  for (int i = 0; i < 4; ++i)
    #pragma unroll
    for (int j = 0; j < 4; ++j) acc[i][j] = (f32x4)(0.f);
  const unsigned short* wrow = Wt  + (size_t)b * kSlots * kTok + (size_t)ar * kTok;
  const unsigned short* vbase = VtT + (size_t)b * kDim * kTok;
  const int fr = lane & 15, kg = (lane >> 4) << 3;

  for (int k0 = 0; k0 < kTok; k0 += 32) {
    *reinterpret_cast<u16x8*>(&As[ar][ac]) = *reinterpret_cast<const u16x8*>(wrow + k0 + ac);
    #pragma unroll
    for (int q = 0; q < 4; ++q) {
      const int ld = ar + 64*q;
      *reinterpret_cast<u16x8*>(&Bs[ld][ac]) =
          *reinterpret_cast<const u16x8*>(vbase + (size_t)(n0 + ld) * kTok + k0 + ac);
    }
    __syncthreads();
    bf16x8 a[4], bb[4];
    #pragma unroll
    for (int mt = 0; mt < 4; ++mt) a[mt] = *reinterpret_cast<const bf16x8*>(&As[mt*16 + fr][kg]);
    #pragma unroll
    for (int nt = 0; nt < 4; ++nt) bb[nt] = *reinterpret_cast<const bf16x8*>(&Bs[wave*64 + nt*16 + fr][kg]);
    #pragma unroll
    for (int mt = 0; mt < 4; ++mt)
      #pragma unroll
      for (int nt = 0; nt < 4; ++nt)
        acc[mt][nt] = __builtin_amdgcn_mfma_f32_16x16x32_bf16(a[mt], bb[nt], acc[mt][nt], 0, 0, 0);
    __syncthreads();
  }
  #pragma unroll
  for (int mt = 0; mt < 4; ++mt) {
    const int s = mt*16 + ((lane >> 4) << 2);
    #pragma unroll
    for (int nt = 0; nt < 4; ++nt) {
      const int d = n0 + wave*64 + nt*16 + (lane & 15);
      #pragma unroll
      for (int r = 0; r < 4; ++r) {
        const size_t off = (size_t)(b*kSlots + s + r) * kDim + d;
        float mo = M[off], gv = G[off];
        M[off] = clipf(0.9f * mo + 0.1f * gv * acc[mt][nt][r], 50.f);
      }
    }
  }
}

// ---------------- final pooling + LN + classifier ------------------------------
__global__ __launch_bounds__(256) void k_final(
    const unsigned short* __restrict__ Wt, const float* __restrict__ M,
    const int* __restrict__ mask, const float* __restrict__ vf,
    const float* __restrict__ lng, const float* __restrict__ lnb,
    const float* __restrict__ clsW, const float* __restrict__ clsb,
    float* __restrict__ out)
{
  __shared__ float red[256];
  __shared__ float wsum[kSlots];
  __shared__ float pooled[kDim];
  __shared__ float sh_mu, sh_var;
  const int b = blockIdx.x, tid = threadIdx.x;
  const unsigned short* wb = Wt + (size_t)b * kSlots * kTok;

  {
    const int s = tid >> 2, c = tid & 3;
    float p = 0.f;
    for (int t = c*128; t < c*128 + 128; ++t)
      if (mask[b*kTok + t] > 0) p += bf2f(wb[(size_t)s * kTok + t]);
    red[tid] = p;
  }
  __syncthreads();
  if (tid < 64) wsum[tid] = red[tid*4] + red[tid*4+1] + red[tid*4+2] + red[tid*4+3];
  __syncthreads();

  const float denom = fmaxf(vf[b], 1.f);
  for (int d = tid; d < kDim; d += 256) {
    float acc = 0.f;
    const float* Mb = M + (size_t)(b*kSlots) * kDim + d;
    #pragma unroll 4
    for (int s = 0; s < kSlots; ++s) acc += wsum[s] * Mb[(size_t)s * kDim];
    pooled[d] = acc / denom;
  }
  __syncthreads();

  float lp = 0.f;
  for (int d = tid; d < kDim; d += 256) lp += pooled[d];
  red[tid] = lp; __syncthreads();
  for (int off = 128; off > 0; off >>= 1) { if (tid < off) red[tid] += red[tid+off]; __syncthreads(); }
  if (tid == 0) sh_mu = red[0] / kDim;
  __syncthreads();
  const float mu = sh_mu;
  float lv = 0.f;
  for (int d = tid; d < kDim; d += 256) { float z = pooled[d] - mu; lv += z*z; }
  red[tid] = lv; __syncthreads();
  for (int off = 128; off > 0; off >>= 1) { if (tid < off) red[tid] += red[tid+off]; __syncthreads(); }
  if (tid == 0) sh_var = red[0] / kDim;
  __syncthreads();
  const float inv = rsqrtf(sh_var + 1e-5f);
  for (int d = tid; d < kDim; d += 256)
    pooled[d] = (pooled[d] - mu) * inv * lng[d] + lnb[d];
  __syncthreads();

  {
    const int c = tid & 7, dg = tid >> 3;
    float part = 0.f;
    for (int d = dg; d < kDim; d += 32) part += pooled[d] * clsW[(size_t)d * kCls + c];
    red[tid] = part;
  }
  __syncthreads();
  if (tid < 8) {
    float s = clsb[tid];
    #pragma unroll
    for (int dg = 0; dg < 32; ++dg) s += red[dg*8 + tid];
    if (!isfinite(s)) s = 0.f;
    out[b*kCls + tid] = s;
  }
}

}  // namespace

extern "C" void kernel_launch(void* const* d_in, const int* in_sizes, int n_in,
                              void* d_out, int out_size, void* d_ws, size_t ws_size,
                              hipStream_t stream)
{
  const int*   ids = (const int*)  d_in[0];
  const int*   msk = (const int*)  d_in[1];
  const float* tok = (const float*)d_in[2];
  const float* pos = (const float*)d_in[3];
  const float* Wq  = (const float*)d_in[4];
  const float* Wk  = (const float*)d_in[5];
  const float* Wv  = (const float*)d_in[6];
  const float* gW  = (const float*)d_in[7];
  const float* gb  = (const float*)d_in[8];
  const float* lng = (const float*)d_in[9];
  const float* lnb = (const float*)d_in[10];
  const float* cW  = (const float*)d_in[11];
  const float* cb  = (const float*)d_in[12];
  const float* mi  = (const float*)d_in[13];
  float* out = (float*)d_out;
  char* base = (char*)d_ws;

  // byte layout (all 256-aligned)
  size_t off = 0;
  unsigned short* Qt  = (unsigned short*)(base + off); off += (size_t)kBatch*kTok*kDim*2;    // 25.2 MB
  unsigned short* VtT = (unsigned short*)(base + off); off += (size_t)kBatch*kDim*kTok*2;    // 25.2 MB
  unsigned short* Km  = (unsigned short*)(base + off); off += (size_t)kBatch*kSlots*kDim*2;  // 3.1 MB
  unsigned short* Wt  = (unsigned short*)(base + off); off += (size_t)kBatch*kSlots*kTok*2;  // 2.1 MB
  unsigned short* WqT = (unsigned short*)(base + off); off += (size_t)kDim*kDim*2;
  unsigned short* WkT = (unsigned short*)(base + off); off += (size_t)kDim*kDim*2;
  unsigned short* WvT = (unsigned short*)(base + off); off += (size_t)kDim*kDim*2;
  unsigned short* gWT = (unsigned short*)(base + off); off += (size_t)kDim*kDim*2;
  float* M  = (float*)(base + off); off += (size_t)kBatch*kSlots*kDim*4;                     // 6.3 MB
  float* G  = (float*)(base + off); off += (size_t)kBatch*kSlots*kDim*4;                     // 6.3 MB
  float* vf = (float*)(base + off); off += 256;

  k_prep<<<dim3(kDim/32, kDim/32, 4), 256, 0, stream>>>(Wq, Wk, Wv, gW, WqT, WkT, WvT, gWT);
  k_minit<<<dim3((kBatch*kSlots*kDim/4)/256), 256, 0, stream>>>(mi, M);
  k_valid<<<dim3(kBatch), 256, 0, stream>>>(msk, vf);
  k_embed_qv<<<dim3(kBatch*kTok/128, kDim/128), 256, 0, stream>>>(ids, tok, pos, WqT, WvT, Qt, VtT);
  for (int it = 0; it < kSteps; ++it) {
    k_mgate<true><<<dim3(kBatch*kSlots/128, kDim/128), 256, 0, stream>>>(M, WkT, gWT, gb, Km, G);
    k_scores<<<dim3(kTok/128, kBatch), 256, 0, stream>>>(Qt, Km, msk, vf, Wt);
    k_write_update<<<dim3(kDim/256, kBatch), 256, 0, stream>>>(Wt, VtT, G, M);
  }
  k_mgate<false><<<dim3(kBatch*kSlots/128, kDim/128), 256, 0, stream>>>(M, WkT, gWT, gb, Km, G);
  k_scores<<<dim3(kTok/128, kBatch), 256, 0, stream>>>(Qt, Km, msk, vf, Wt);
  k_final<<<dim3(kBatch), 256, 0, stream>>>(Wt, M, msk, vf, lng, lnb, cW, cb, out);

  (void)in_sizes; (void)n_in; (void)out_size; (void)ws_size;
}

// Round 6
// 679.658 us; speedup vs baseline: 2.1563x; 1.0857x over previous
//
#include <hip/hip_runtime.h>
#include <math.h>

namespace {

constexpr int kBatch = 32;
constexpr int kTok   = 512;
constexpr int kDim   = 768;
constexpr int kSlots = 64;
constexpr int kSteps = 4;
constexpr int kCls   = 8;
constexpr float kScale = 0.03608439182435161f;  // 1/sqrt(768)
constexpr int kPad   = 40;                      // LDS row stride in u16: 80B, bank-conflict-free

typedef __attribute__((ext_vector_type(4))) float f32x4;
typedef __attribute__((ext_vector_type(8))) short bf16x8;      // 8 bf16 (4 VGPRs)
typedef __attribute__((ext_vector_type(8))) unsigned short u16x8;
typedef __attribute__((ext_vector_type(4))) unsigned short u16x4;

__device__ __forceinline__ float clipf(float x, float c) { return fminf(fmaxf(x, -c), c); }
__device__ __forceinline__ unsigned short f2bf(float f) {
  unsigned u = __float_as_uint(f);
  return (unsigned short)((u + 0x7fffu + ((u >> 16) & 1u)) >> 16);  // RNE
}
__device__ __forceinline__ float bf2f(unsigned short h) {
  return __uint_as_float(((unsigned)h) << 16);
}

// ---------------- weight transpose + cvt: W[768][768] f32 -> WT[768][768] bf16 --
__global__ __launch_bounds__(256) void k_prep(
    const float* __restrict__ Wq, const float* __restrict__ Wk,
    const float* __restrict__ Wv, const float* __restrict__ gW,
    unsigned short* __restrict__ WqT, unsigned short* __restrict__ WkT,
    unsigned short* __restrict__ WvT, unsigned short* __restrict__ gWT)
{
  __shared__ float tile[32][33];
  const int mat = blockIdx.z;
  const float* src = (mat == 0) ? Wq : (mat == 1) ? Wk : (mat == 2) ? Wv : gW;
  unsigned short* dst = (mat == 0) ? WqT : (mat == 1) ? WkT : (mat == 2) ? WvT : gWT;
  const int tx = threadIdx.x & 31, ty = threadIdx.x >> 5;
  const int r0 = blockIdx.y * 32, c0 = blockIdx.x * 32;
  #pragma unroll
  for (int q = 0; q < 4; ++q)
    tile[ty + 8*q][tx] = src[(size_t)(r0 + ty + 8*q) * kDim + c0 + tx];
  __syncthreads();
  #pragma unroll
  for (int q = 0; q < 4; ++q)
    dst[(size_t)(c0 + ty + 8*q) * kDim + r0 + tx] = f2bf(tile[tx][ty + 8*q]);
}

// ---------------- M init -------------------------------------------------------
__global__ __launch_bounds__(256) void k_minit(const float* __restrict__ mi, float* __restrict__ M) {
  int i = blockIdx.x * 256 + threadIdx.x;
  constexpr int per = kSlots * kDim / 4;
  float4 v = reinterpret_cast<const float4*>(mi)[i % per];
  reinterpret_cast<float4*>(M)[i] = v;
}

// ---------------- valid[b] -----------------------------------------------------
__global__ __launch_bounds__(256) void k_valid(const int* __restrict__ mask, float* __restrict__ vf) {
  __shared__ float red[256];
  const int b = blockIdx.x, tid = threadIdx.x;
  float c = 0.f;
  for (int t = tid; t < kTok; t += 256) c += (mask[b*kTok + t] > 0) ? 1.f : 0.f;
  red[tid] = c; __syncthreads();
  for (int off = 128; off > 0; off >>= 1) { if (tid < off) red[tid] += red[tid+off]; __syncthreads(); }
  if (tid == 0) vf[b] = red[0];
}

// ---------------- Qt = x@Wq, VtT = (x@Wv)^T  (MFMA, dual B, prefetched) --------
// grid (16384/128, 768/128), 256 thr = 4 waves in 2x2, each wave 64x64 per output
__global__ __launch_bounds__(256) void k_embed_qv(
    const int* __restrict__ ids, const float* __restrict__ tok, const float* __restrict__ pos,
    const unsigned short* __restrict__ WqT, const unsigned short* __restrict__ WvT,
    unsigned short* __restrict__ Qt, unsigned short* __restrict__ VtT)
{
  __shared__ unsigned short As[128][kPad];
  __shared__ unsigned short Bq[128][kPad];
  __shared__ unsigned short Bv[128][kPad];
  __shared__ int rid[128];
  const int tid = threadIdx.x;
  const int m0 = blockIdx.x * 128, n0 = blockIdx.y * 128;
  if (tid < 128) rid[tid] = ids[m0 + tid];
  const int wave = tid >> 6, lane = tid & 63;
  const int wr = wave >> 1, wc = wave & 1;
  const int ar = tid >> 1, ac = (tid & 1) << 4;   // staging: row, 16-col group
  f32x4 accq[4][4], accv[4][4];
  #pragma unroll
  for (int i = 0; i < 4; ++i)
    #pragma unroll
    for (int j = 0; j < 4; ++j) { accq[i][j] = (f32x4)(0.f); accv[i][j] = (f32x4)(0.f); }
  __syncthreads();
  const float* tokrow = tok + (size_t)rid[ar] * kDim;
  const float* posrow = pos + (size_t)((m0 + ar) & (kTok - 1)) * kDim;
  const unsigned short* bqrow = WqT + (size_t)(n0 + ar) * kDim;
  const unsigned short* bvrow = WvT + (size_t)(n0 + ar) * kDim;
  const int fr = lane & 15, kg = (lane >> 4) << 3;

  // prefetch registers (k0 = 0)
  float4 tv[4], pv[4];
  u16x8 pq[2], pvv[2];
  #pragma unroll
  for (int q = 0; q < 4; ++q) {
    tv[q] = *reinterpret_cast<const float4*>(tokrow + ac + 4*q);
    pv[q] = *reinterpret_cast<const float4*>(posrow + ac + 4*q);
  }
  pq[0]  = *reinterpret_cast<const u16x8*>(bqrow + ac);
  pq[1]  = *reinterpret_cast<const u16x8*>(bqrow + ac + 8);
  pvv[0] = *reinterpret_cast<const u16x8*>(bvrow + ac);
  pvv[1] = *reinterpret_cast<const u16x8*>(bvrow + ac + 8);

  for (int k0 = 0; k0 < kDim; k0 += 32) {
    unsigned short av[16];
    #pragma unroll
    for (int q = 0; q < 4; ++q) {
      av[4*q+0] = f2bf(tv[q].x + pv[q].x); av[4*q+1] = f2bf(tv[q].y + pv[q].y);
      av[4*q+2] = f2bf(tv[q].z + pv[q].z); av[4*q+3] = f2bf(tv[q].w + pv[q].w);
    }
    *reinterpret_cast<u16x8*>(&As[ar][ac])     = *reinterpret_cast<u16x8*>(&av[0]);
    *reinterpret_cast<u16x8*>(&As[ar][ac + 8]) = *reinterpret_cast<u16x8*>(&av[8]);
    *reinterpret_cast<u16x8*>(&Bq[ar][ac])     = pq[0];
    *reinterpret_cast<u16x8*>(&Bq[ar][ac + 8]) = pq[1];
    *reinterpret_cast<u16x8*>(&Bv[ar][ac])     = pvv[0];
    *reinterpret_cast<u16x8*>(&Bv[ar][ac + 8]) = pvv[1];
    __syncthreads();
    if (k0 + 32 < kDim) {  // issue next-tile loads; latency hides under MFMAs
      const int kn = k0 + 32;
      #pragma unroll
      for (int q = 0; q < 4; ++q) {
        tv[q] = *reinterpret_cast<const float4*>(tokrow + kn + ac + 4*q);
        pv[q] = *reinterpret_cast<const float4*>(posrow + kn + ac + 4*q);
      }
      pq[0]  = *reinterpret_cast<const u16x8*>(bqrow + kn + ac);
      pq[1]  = *reinterpret_cast<const u16x8*>(bqrow + kn + ac + 8);
      pvv[0] = *reinterpret_cast<const u16x8*>(bvrow + kn + ac);
      pvv[1] = *reinterpret_cast<const u16x8*>(bvrow + kn + ac + 8);
    }
    bf16x8 a[4], bq[4], bv[4];
    #pragma unroll
    for (int mt = 0; mt < 4; ++mt) a[mt] = *reinterpret_cast<const bf16x8*>(&As[wr*64 + mt*16 + fr][kg]);
    #pragma unroll
    for (int nt = 0; nt < 4; ++nt) {
      bq[nt] = *reinterpret_cast<const bf16x8*>(&Bq[wc*64 + nt*16 + fr][kg]);
      bv[nt] = *reinterpret_cast<const bf16x8*>(&Bv[wc*64 + nt*16 + fr][kg]);
    }
    #pragma unroll
    for (int mt = 0; mt < 4; ++mt)
      #pragma unroll
      for (int nt = 0; nt < 4; ++nt) {
        accq[mt][nt] = __builtin_amdgcn_mfma_f32_16x16x32_bf16(a[mt], bq[nt], accq[mt][nt], 0, 0, 0);
        accv[mt][nt] = __builtin_amdgcn_mfma_f32_16x16x32_bf16(a[mt], bv[nt], accv[mt][nt], 0, 0, 0);
      }
    __syncthreads();
  }
  // Qt[t][d] bf16 (scattered 2B); VtT[b][d][t] bf16 (8B packed along t)
  const int b = m0 >> 9;
  unsigned short* vb = VtT + (size_t)b * kDim * kTok;
  #pragma unroll
  for (int mt = 0; mt < 4; ++mt) {
    const int trow = m0 + wr*64 + mt*16 + ((lane >> 4) << 2);
    const int tloc = (trow & (kTok - 1));
    #pragma unroll
    for (int nt = 0; nt < 4; ++nt) {
      const int dcol = n0 + wc*64 + nt*16 + (lane & 15);
      u16x4 pk;
      #pragma unroll
      for (int r = 0; r < 4; ++r) {
        Qt[(size_t)(trow + r) * kDim + dcol] = f2bf(accq[mt][nt][r]);
        pk[r] = f2bf(accv[mt][nt][r]);
      }
      *reinterpret_cast<u16x4*>(vb + (size_t)dcol * kTok + tloc) = pk;
    }
  }
}

// ---------------- Km = M@Wk (+ G = sigmoid(M@gate_W + gb)) ---------------------
// wave-per-block: 64 thr, 64x64 tile, grid (2048/64=32, 768/64=12) = 384 blocks
template <bool DO_GATE>
__global__ __launch_bounds__(64) void k_mgate(
    const float* __restrict__ M, const unsigned short* __restrict__ WkT,
    const unsigned short* __restrict__ gWT, const float* __restrict__ gb,
    unsigned short* __restrict__ Km, float* __restrict__ G)
{
  __shared__ unsigned short As[64][kPad];
  __shared__ unsigned short Bk[64][kPad];
  __shared__ unsigned short Bg[64][kPad];
  const int lane = threadIdx.x;
  const int m0 = blockIdx.x * 64, n0 = blockIdx.y * 64;
  const int fr = lane & 15, kg = (lane >> 4) << 3, crow = (lane >> 4) << 2;
  f32x4 acck[4][4], accg[4][4];
  #pragma unroll
  for (int i = 0; i < 4; ++i)
    #pragma unroll
    for (int j = 0; j < 4; ++j) { acck[i][j] = (f32x4)(0.f); accg[i][j] = (f32x4)(0.f); }
  const float* arow = M + (size_t)(m0 + lane) * kDim;
  const unsigned short* bkrow = WkT + (size_t)(n0 + lane) * kDim;
  const unsigned short* bgrow = gWT + (size_t)(n0 + lane) * kDim;

  for (int k0 = 0; k0 < kDim; k0 += 32) {
    unsigned short av[32];
    #pragma unroll
    for (int q = 0; q < 8; ++q) {
      float4 v = *reinterpret_cast<const float4*>(arow + k0 + 4*q);
      av[4*q+0] = f2bf(v.x); av[4*q+1] = f2bf(v.y); av[4*q+2] = f2bf(v.z); av[4*q+3] = f2bf(v.w);
    }
    #pragma unroll
    for (int h = 0; h < 4; ++h)
      *reinterpret_cast<u16x8*>(&As[lane][8*h]) = *reinterpret_cast<u16x8*>(&av[8*h]);
    #pragma unroll
    for (int h = 0; h < 4; ++h)
      *reinterpret_cast<u16x8*>(&Bk[lane][8*h]) = *reinterpret_cast<const u16x8*>(bkrow + k0 + 8*h);
    if (DO_GATE) {
      #pragma unroll
      for (int h = 0; h < 4; ++h)
        *reinterpret_cast<u16x8*>(&Bg[lane][8*h]) = *reinterpret_cast<const u16x8*>(bgrow + k0 + 8*h);
    }
    __syncthreads();
    bf16x8 a[4], bk[4], bg[4];
    #pragma unroll
    for (int mt = 0; mt < 4; ++mt) a[mt] = *reinterpret_cast<const bf16x8*>(&As[mt*16 + fr][kg]);
    #pragma unroll
    for (int nt = 0; nt < 4; ++nt) {
      bk[nt] = *reinterpret_cast<const bf16x8*>(&Bk[nt*16 + fr][kg]);
      if (DO_GATE) bg[nt] = *reinterpret_cast<const bf16x8*>(&Bg[nt*16 + fr][kg]);
    }
    #pragma unroll
    for (int mt = 0; mt < 4; ++mt)
      #pragma unroll
      for (int nt = 0; nt < 4; ++nt) {
        acck[mt][nt] = __builtin_amdgcn_mfma_f32_16x16x32_bf16(a[mt], bk[nt], acck[mt][nt], 0, 0, 0);
        if (DO_GATE) accg[mt][nt] = __builtin_amdgcn_mfma_f32_16x16x32_bf16(a[mt], bg[nt], accg[mt][nt], 0, 0, 0);
      }
    __syncthreads();
  }
  #pragma unroll
  for (int mt = 0; mt < 4; ++mt) {
    const int row = m0 + mt*16 + crow;
    #pragma unroll
    for (int nt = 0; nt < 4; ++nt) {
      const int col = n0 + nt*16 + fr;
      #pragma unroll
      for (int r = 0; r < 4; ++r) {
        Km[(size_t)(row + r) * kDim + col] = f2bf(acck[mt][nt][r]);
        if (DO_GATE) {
          float z = accg[mt][nt][r] + gb[col];
          G[(size_t)(row + r) * kDim + col] = 1.f / (1.f + __expf(-z));
        }
      }
    }
  }
}

// ---------------- scores -> masked softmax -> Wt[b][s][t] ----------------------
// wave-per-block: 64 thr, 32 t-rows x 64 slots, grid (512/32=16, 32) = 512 blocks
__global__ __launch_bounds__(64) void k_scores(
    const unsigned short* __restrict__ Qt, const unsigned short* __restrict__ Km,
    const int* __restrict__ mask, const float* __restrict__ vf,
    unsigned short* __restrict__ Wt)
{
  __shared__ unsigned short As[32][kPad];
  __shared__ unsigned short Bs[64][kPad];
  const int lane = threadIdx.x;
  const int b = blockIdx.y, t0 = blockIdx.x * 32;
  const int fr = lane & 15, kg = (lane >> 4) << 3, crow = (lane >> 4) << 2;
  const int ac = (lane & 1) << 4;
  f32x4 acc[2][4];
  #pragma unroll
  for (int i = 0; i < 2; ++i)
    #pragma unroll
    for (int j = 0; j < 4; ++j) acc[i][j] = (f32x4)(0.f);
  const unsigned short* qrow = Qt + (size_t)(b*kTok + t0 + (lane >> 1)) * kDim;
  const unsigned short* krow = Km + (size_t)(b*kSlots + lane) * kDim;

  for (int k0 = 0; k0 < kDim; k0 += 32) {
    *reinterpret_cast<u16x8*>(&As[lane >> 1][ac])     = *reinterpret_cast<const u16x8*>(qrow + k0 + ac);
    *reinterpret_cast<u16x8*>(&As[lane >> 1][ac + 8]) = *reinterpret_cast<const u16x8*>(qrow + k0 + ac + 8);
    #pragma unroll
    for (int h = 0; h < 4; ++h)
      *reinterpret_cast<u16x8*>(&Bs[lane][8*h]) = *reinterpret_cast<const u16x8*>(krow + k0 + 8*h);
    __syncthreads();
    bf16x8 a[2], bb[4];
    #pragma unroll
    for (int mt = 0; mt < 2; ++mt) a[mt] = *reinterpret_cast<const bf16x8*>(&As[mt*16 + fr][kg]);
    #pragma unroll
    for (int nt = 0; nt < 4; ++nt) bb[nt] = *reinterpret_cast<const bf16x8*>(&Bs[nt*16 + fr][kg]);
    #pragma unroll
    for (int mt = 0; mt < 2; ++mt)
      #pragma unroll
      for (int nt = 0; nt < 4; ++nt)
        acc[mt][nt] = __builtin_amdgcn_mfma_f32_16x16x32_bf16(a[mt], bb[nt], acc[mt][nt], 0, 0, 0);
    __syncthreads();
  }
  // clip + softmax over s (row = fixed t), mask factor
  #pragma unroll
  for (int mt = 0; mt < 2; ++mt)
    #pragma unroll
    for (int nt = 0; nt < 4; ++nt)
      #pragma unroll
      for (int r = 0; r < 4; ++r)
        acc[mt][nt][r] = clipf(acc[mt][nt][r] * kScale, 20.f);
  const float vfb = vf[b];
  float fac[2][4];
  #pragma unroll
  for (int mt = 0; mt < 2; ++mt) {
    #pragma unroll
    for (int r = 0; r < 4; ++r) {
      float mx = fmaxf(fmaxf(acc[mt][0][r], acc[mt][1][r]), fmaxf(acc[mt][2][r], acc[mt][3][r]));
      #pragma unroll
      for (int m = 1; m < 16; m <<= 1) mx = fmaxf(mx, __shfl_xor(mx, m, 64));
      float sum = 0.f;
      #pragma unroll
      for (int nt = 0; nt < 4; ++nt) { float e = __expf(acc[mt][nt][r] - mx); acc[mt][nt][r] = e; sum += e; }
      #pragma unroll
      for (int m = 1; m < 16; m <<= 1) sum += __shfl_xor(sum, m, 64);
      const int tloc = t0 + mt*16 + crow + r;
      const bool keep = (mask[b*kTok + tloc] > 0) || (vfb == 0.f);
      fac[mt][r] = keep ? (1.f / sum) : 0.f;
    }
  }
  unsigned short* wb = Wt + (size_t)b * kSlots * kTok;
  #pragma unroll
  for (int mt = 0; mt < 2; ++mt) {
    const int tbase = t0 + mt*16 + crow;
    #pragma unroll
    for (int nt = 0; nt < 4; ++nt) {
      const int s = nt*16 + fr;
      u16x4 pk;
      #pragma unroll
      for (int r = 0; r < 4; ++r) pk[r] = f2bf(acc[mt][nt][r] * fac[mt][r]);
      *reinterpret_cast<u16x4*>(wb + (size_t)s * kTok + tbase) = pk;
    }
  }
}

// ---------------- write = Wt @ VtT^T fused with M update -----------------------
// wave-per-block: 64 thr, 64 slots x 64 d, grid (768/64=12, 32) = 384 blocks
__global__ __launch_bounds__(64) void k_write_update(
    const unsigned short* __restrict__ Wt, const unsigned short* __restrict__ VtT,
    const float* __restrict__ G, float* __restrict__ M)
{
  __shared__ unsigned short As[64][kPad];
  __shared__ unsigned short Bs[64][kPad];
  const int lane = threadIdx.x;
  const int b = blockIdx.y, n0 = blockIdx.x * 64;
  const int fr = lane & 15, kg = (lane >> 4) << 3, crow = (lane >> 4) << 2;
  f32x4 acc[4][4];
  #pragma unroll
  for (int i = 0; i < 4; ++i)
    #pragma unroll
    for (int j = 0; j < 4; ++j) acc[i][j] = (f32x4)(0.f);
  const unsigned short* wrow = Wt  + (size_t)b * kSlots * kTok + (size_t)lane * kTok;
  const unsigned short* vrow = VtT + (size_t)b * kDim * kTok + (size_t)(n0 + lane) * kTok;

  for (int k0 = 0; k0 < kTok; k0 += 32) {
    #pragma unroll
    for (int h = 0; h < 4; ++h)
      *reinterpret_cast<u16x8*>(&As[lane][8*h]) = *reinterpret_cast<const u16x8*>(wrow + k0 + 8*h);
    #pragma unroll
    for (int h = 0; h < 4; ++h)
      *reinterpret_cast<u16x8*>(&Bs[lane][8*h]) = *reinterpret_cast<const u16x8*>(vrow + k0 + 8*h);
    __syncthreads();
    bf16x8 a[4], bb[4];
    #pragma unroll
    for (int mt = 0; mt < 4; ++mt) a[mt] = *reinterpret_cast<const bf16x8*>(&As[mt*16 + fr][kg]);
    #pragma unroll
    for (int nt = 0; nt < 4; ++nt) bb[nt] = *reinterpret_cast<const bf16x8*>(&Bs[nt*16 + fr][kg]);
    #pragma unroll
    for (int mt = 0; mt < 4; ++mt)
      #pragma unroll
      for (int nt = 0; nt < 4; ++nt)
        acc[mt][nt] = __builtin_amdgcn_mfma_f32_16x16x32_bf16(a[mt], bb[nt], acc[mt][nt], 0, 0, 0);
    __syncthreads();
  }
  #pragma unroll
  for (int mt = 0; mt < 4; ++mt) {
    const int s = mt*16 + crow;
    #pragma unroll
    for (int nt = 0; nt < 4; ++nt) {
      const int d = n0 + nt*16 + fr;
      #pragma unroll
      for (int r = 0; r < 4; ++r) {
        const size_t off = (size_t)(b*kSlots + s + r) * kDim + d;
        float mo = M[off], gv = G[off];
        M[off] = clipf(0.9f * mo + 0.1f * gv * acc[mt][nt][r], 50.f);
      }
    }
  }
}

// ---------------- final pooling + LN + classifier ------------------------------
__global__ __launch_bounds__(256) void k_final(
    const unsigned short* __restrict__ Wt, const float* __restrict__ M,
    const int* __restrict__ mask, const float* __restrict__ vf,
    const float* __restrict__ lng, const float* __restrict__ lnb,
    const float* __restrict__ clsW, const float* __restrict__ clsb,
    float* __restrict__ out)
{
  __shared__ float red[256];
  __shared__ float wsum[kSlots];
  __shared__ float pooled[kDim];
  __shared__ float sh_mu, sh_var;
  const int b = blockIdx.x, tid = threadIdx.x;
  const unsigned short* wb = Wt + (size_t)b * kSlots * kTok;

  {
    const int s = tid >> 2, c = tid & 3;
    float p = 0.f;
    for (int t = c*128; t < c*128 + 128; ++t)
      if (mask[b*kTok + t] > 0) p += bf2f(wb[(size_t)s * kTok + t]);
    red[tid] = p;
  }
  __syncthreads();
  if (tid < 64) wsum[tid] = red[tid*4] + red[tid*4+1] + red[tid*4+2] + red[tid*4+3];
  __syncthreads();

  const float denom = fmaxf(vf[b], 1.f);
  for (int d = tid; d < kDim; d += 256) {
    float acc = 0.f;
    const float* Mb = M + (size_t)(b*kSlots) * kDim + d;
    #pragma unroll 4
    for (int s = 0; s < kSlots; ++s) acc += wsum[s] * Mb[(size_t)s * kDim];
    pooled[d] = acc / denom;
  }
  __syncthreads();

  float lp = 0.f;
  for (int d = tid; d < kDim; d += 256) lp += pooled[d];
  red[tid] = lp; __syncthreads();
  for (int off = 128; off > 0; off >>= 1) { if (tid < off) red[tid] += red[tid+off]; __syncthreads(); }
  if (tid == 0) sh_mu = red[0] / kDim;
  __syncthreads();
  const float mu = sh_mu;
  float lv = 0.f;
  for (int d = tid; d < kDim; d += 256) { float z = pooled[d] - mu; lv += z*z; }
  red[tid] = lv; __syncthreads();
  for (int off = 128; off > 0; off >>= 1) { if (tid < off) red[tid] += red[tid+off]; __syncthreads(); }
  if (tid == 0) sh_var = red[0] / kDim;
  __syncthreads();
  const float inv = rsqrtf(sh_var + 1e-5f);
  for (int d = tid; d < kDim; d += 256)
    pooled[d] = (pooled[d] - mu) * inv * lng[d] + lnb[d];
  __syncthreads();

  {
    const int c = tid & 7, dg = tid >> 3;
    float part = 0.f;
    for (int d = dg; d < kDim; d += 32) part += pooled[d] * clsW[(size_t)d * kCls + c];
    red[tid] = part;
  }
  __syncthreads();
  if (tid < 8) {
    float s = clsb[tid];
    #pragma unroll
    for (int dg = 0; dg < 32; ++dg) s += red[dg*8 + tid];
    if (!isfinite(s)) s = 0.f;
    out[b*kCls + tid] = s;
  }
}

}  // namespace

extern "C" void kernel_launch(void* const* d_in, const int* in_sizes, int n_in,
                              void* d_out, int out_size, void* d_ws, size_t ws_size,
                              hipStream_t stream)
{
  const int*   ids = (const int*)  d_in[0];
  const int*   msk = (const int*)  d_in[1];
  const float* tok = (const float*)d_in[2];
  const float* pos = (const float*)d_in[3];
  const float* Wq  = (const float*)d_in[4];
  const float* Wk  = (const float*)d_in[5];
  const float* Wv  = (const float*)d_in[6];
  const float* gW  = (const float*)d_in[7];
  const float* gb  = (const float*)d_in[8];
  const float* lng = (const float*)d_in[9];
  const float* lnb = (const float*)d_in[10];
  const float* cW  = (const float*)d_in[11];
  const float* cb  = (const float*)d_in[12];
  const float* mi  = (const float*)d_in[13];
  float* out = (float*)d_out;
  char* base = (char*)d_ws;

  // byte layout (all 256-aligned)
  size_t off = 0;
  unsigned short* Qt  = (unsigned short*)(base + off); off += (size_t)kBatch*kTok*kDim*2;    // 25.2 MB
  unsigned short* VtT = (unsigned short*)(base + off); off += (size_t)kBatch*kDim*kTok*2;    // 25.2 MB
  unsigned short* Km  = (unsigned short*)(base + off); off += (size_t)kBatch*kSlots*kDim*2;  // 3.1 MB
  unsigned short* Wt  = (unsigned short*)(base + off); off += (size_t)kBatch*kSlots*kTok*2;  // 2.1 MB
  unsigned short* WqT = (unsigned short*)(base + off); off += (size_t)kDim*kDim*2;
  unsigned short* WkT = (unsigned short*)(base + off); off += (size_t)kDim*kDim*2;
  unsigned short* WvT = (unsigned short*)(base + off); off += (size_t)kDim*kDim*2;
  unsigned short* gWT = (unsigned short*)(base + off); off += (size_t)kDim*kDim*2;
  float* M  = (float*)(base + off); off += (size_t)kBatch*kSlots*kDim*4;                     // 6.3 MB
  float* G  = (float*)(base + off); off += (size_t)kBatch*kSlots*kDim*4;                     // 6.3 MB
  float* vf = (float*)(base + off); off += 256;

  k_prep<<<dim3(kDim/32, kDim/32, 4), 256, 0, stream>>>(Wq, Wk, Wv, gW, WqT, WkT, WvT, gWT);
  k_minit<<<dim3((kBatch*kSlots*kDim/4)/256), 256, 0, stream>>>(mi, M);
  k_valid<<<dim3(kBatch), 256, 0, stream>>>(msk, vf);
  k_embed_qv<<<dim3(kBatch*kTok/128, kDim/128), 256, 0, stream>>>(ids, tok, pos, WqT, WvT, Qt, VtT);
  for (int it = 0; it < kSteps; ++it) {
    k_mgate<true><<<dim3(kBatch*kSlots/64, kDim/64), 64, 0, stream>>>(M, WkT, gWT, gb, Km, G);
    k_scores<<<dim3(kTok/32, kBatch), 64, 0, stream>>>(Qt, Km, msk, vf, Wt);
    k_write_update<<<dim3(kDim/64, kBatch), 64, 0, stream>>>(Wt, VtT, G, M);
  }
  k_mgate<false><<<dim3(kBatch*kSlots/64, kDim/64), 64, 0, stream>>>(M, WkT, gWT, gb, Km, G);
  k_scores<<<dim3(kTok/32, kBatch), 64, 0, stream>>>(Qt, Km, msk, vf, Wt);
  k_final<<<dim3(kBatch), 256, 0, stream>>>(Wt, M, msk, vf, lng, lnb, cW, cb, out);

  (void)in_sizes; (void)n_in; (void)out_size; (void)ws_size;
}

// Round 7
// 538.573 us; speedup vs baseline: 2.7212x; 1.2620x over previous
//
#include <hip/hip_runtime.h>
#include <math.h>

namespace {

constexpr int kBatch = 32;
constexpr int kTok   = 512;
constexpr int kDim   = 768;
constexpr int kSlots = 64;
constexpr int kSteps = 4;
constexpr int kCls   = 8;
constexpr float kScale = 0.03608439182435161f;  // 1/sqrt(768)
constexpr int kPad   = 40;                      // LDS row stride in u16

typedef __attribute__((ext_vector_type(4))) float f32x4;
typedef __attribute__((ext_vector_type(8))) short bf16x8;
typedef __attribute__((ext_vector_type(8))) unsigned short u16x8;
typedef __attribute__((ext_vector_type(4))) unsigned short u16x4;

__device__ __forceinline__ float clipf(float x, float c) { return fminf(fmaxf(x, -c), c); }
__device__ __forceinline__ unsigned short f2bf(float f) {
  unsigned u = __float_as_uint(f);
  return (unsigned short)((u + 0x7fffu + ((u >> 16) & 1u)) >> 16);  // RNE
}
__device__ __forceinline__ float bf2f(unsigned short h) {
  return __uint_as_float(((unsigned)h) << 16);
}

// ---------------- transpose+cvt: Wv, gW -> WvT, gWT (bf16 [out][in]) -----------
__global__ __launch_bounds__(256) void k_prep(
    const float* __restrict__ Wv, const float* __restrict__ gW,
    unsigned short* __restrict__ WvT, unsigned short* __restrict__ gWT)
{
  __shared__ float tile[32][33];
  const int mat = blockIdx.z;
  const float* src = (mat == 0) ? Wv : gW;
  unsigned short* dst = (mat == 0) ? WvT : gWT;
  const int tx = threadIdx.x & 31, ty = threadIdx.x >> 5;
  const int r0 = blockIdx.y * 32, c0 = blockIdx.x * 32;
  #pragma unroll
  for (int q = 0; q < 4; ++q)
    tile[ty + 8*q][tx] = src[(size_t)(r0 + ty + 8*q) * kDim + c0 + tx];
  __syncthreads();
  #pragma unroll
  for (int q = 0; q < 4; ++q)
    dst[(size_t)(c0 + ty + 8*q) * kDim + r0 + tx] = f2bf(tile[tx][ty + 8*q]);
}

// ---------------- WqkT[d][e] = sum_c Wk[d][c] * Wq[e][c]  (NT MFMA, once) ------
__global__ __launch_bounds__(64) void k_wqk(
    const float* __restrict__ Wk, const float* __restrict__ Wq,
    unsigned short* __restrict__ WqkT)
{
  __shared__ unsigned short As[64][kPad];
  __shared__ unsigned short Bs[64][kPad];
  const int lane = threadIdx.x;
  const int m0 = blockIdx.x * 64, n0 = blockIdx.y * 64;
  const int fr = lane & 15, kg = (lane >> 4) << 3, crow = (lane >> 4) << 2;
  f32x4 acc[4][4];
  #pragma unroll
  for (int i = 0; i < 4; ++i)
    #pragma unroll
    for (int j = 0; j < 4; ++j) acc[i][j] = (f32x4)(0.f);
  const float* arow = Wk + (size_t)(m0 + lane) * kDim;
  const float* brow = Wq + (size_t)(n0 + lane) * kDim;
  for (int k0 = 0; k0 < kDim; k0 += 32) {
    unsigned short av[32], bv[32];
    #pragma unroll
    for (int q = 0; q < 8; ++q) {
      float4 a4 = *reinterpret_cast<const float4*>(arow + k0 + 4*q);
      float4 b4 = *reinterpret_cast<const float4*>(brow + k0 + 4*q);
      av[4*q+0]=f2bf(a4.x); av[4*q+1]=f2bf(a4.y); av[4*q+2]=f2bf(a4.z); av[4*q+3]=f2bf(a4.w);
      bv[4*q+0]=f2bf(b4.x); bv[4*q+1]=f2bf(b4.y); bv[4*q+2]=f2bf(b4.z); bv[4*q+3]=f2bf(b4.w);
    }
    #pragma unroll
    for (int h = 0; h < 4; ++h) {
      *reinterpret_cast<u16x8*>(&As[lane][8*h]) = *reinterpret_cast<u16x8*>(&av[8*h]);
      *reinterpret_cast<u16x8*>(&Bs[lane][8*h]) = *reinterpret_cast<u16x8*>(&bv[8*h]);
    }
    __syncthreads();
    bf16x8 a[4], bb[4];
    #pragma unroll
    for (int mt = 0; mt < 4; ++mt) a[mt] = *reinterpret_cast<const bf16x8*>(&As[mt*16 + fr][kg]);
    #pragma unroll
    for (int nt = 0; nt < 4; ++nt) bb[nt] = *reinterpret_cast<const bf16x8*>(&Bs[nt*16 + fr][kg]);
    #pragma unroll
    for (int mt = 0; mt < 4; ++mt)
      #pragma unroll
      for (int nt = 0; nt < 4; ++nt)
        acc[mt][nt] = __builtin_amdgcn_mfma_f32_16x16x32_bf16(a[mt], bb[nt], acc[mt][nt], 0, 0, 0);
    __syncthreads();
  }
  #pragma unroll
  for (int mt = 0; mt < 4; ++mt) {
    const int row = m0 + mt*16 + crow;
    #pragma unroll
    for (int nt = 0; nt < 4; ++nt) {
      const int col = n0 + nt*16 + fr;
      #pragma unroll
      for (int r = 0; r < 4; ++r)
        WqkT[(size_t)(row + r) * kDim + col] = f2bf(acc[mt][nt][r]);
    }
  }
}

// ---------------- M init: f32 + bf16 copies ------------------------------------
__global__ __launch_bounds__(256) void k_minit(
    const float* __restrict__ mi, float* __restrict__ M, unsigned short* __restrict__ Mb)
{
  int i = blockIdx.x * 256 + threadIdx.x;           // float4 index
  constexpr int per = kSlots * kDim / 4;
  float4 v = reinterpret_cast<const float4*>(mi)[i % per];
  reinterpret_cast<float4*>(M)[i] = v;
  u16x4 p; p[0]=f2bf(v.x); p[1]=f2bf(v.y); p[2]=f2bf(v.z); p[3]=f2bf(v.w);
  *reinterpret_cast<u16x4*>(Mb + (size_t)i*4) = p;
}

// ---------------- valid[b] -----------------------------------------------------
__global__ __launch_bounds__(256) void k_valid(const int* __restrict__ mask, float* __restrict__ vf) {
  __shared__ float red[256];
  const int b = blockIdx.x, tid = threadIdx.x;
  float c = 0.f;
  for (int t = tid; t < kTok; t += 256) c += (mask[b*kTok + t] > 0) ? 1.f : 0.f;
  red[tid] = c; __syncthreads();
  for (int off = 128; off > 0; off >>= 1) { if (tid < off) red[tid] += red[tid+off]; __syncthreads(); }
  if (tid == 0) vf[b] = red[0];
}

// ---------------- Qk = x@Wqk, VtT = (x@Wv)^T  (BM=64, BN=128, 4 waves) ---------
// grid (16384/64=256, 768/128=6) = 1536 blocks
__global__ __launch_bounds__(256) void k_embed_qv(
    const int* __restrict__ ids, const float* __restrict__ tok, const float* __restrict__ pos,
    const unsigned short* __restrict__ WqkT, const unsigned short* __restrict__ WvT,
    unsigned short* __restrict__ Qk, unsigned short* __restrict__ VtT)
{
  __shared__ unsigned short As[64][kPad];
  __shared__ unsigned short Bq[128][kPad];
  __shared__ unsigned short Bv[128][kPad];
  __shared__ int rid[64];
  const int tid = threadIdx.x;
  const int m0 = blockIdx.x * 64, n0 = blockIdx.y * 128;
  if (tid < 64) rid[tid] = ids[m0 + tid];
  const int wave = tid >> 6, lane = tid & 63;
  const int ar = tid >> 2, ac = (tid & 3) << 3;   // A staging: row, 8-col group
  const int br = tid >> 1, bc = (tid & 1) << 4;   // B staging: row, 16-col group
  const int fr = lane & 15, kg = (lane >> 4) << 3, crow = (lane >> 4) << 2;
  f32x4 accq[4][2], accv[4][2];
  #pragma unroll
  for (int i = 0; i < 4; ++i)
    #pragma unroll
    for (int j = 0; j < 2; ++j) { accq[i][j] = (f32x4)(0.f); accv[i][j] = (f32x4)(0.f); }
  __syncthreads();
  const float* tokrow = tok + (size_t)rid[ar] * kDim;
  const float* posrow = pos + (size_t)((m0 + ar) & (kTok - 1)) * kDim;
  const unsigned short* bqrow = WqkT + (size_t)(n0 + br) * kDim;
  const unsigned short* bvrow = WvT  + (size_t)(n0 + br) * kDim;

  // prefetch k0 = 0
  float4 tv0 = *reinterpret_cast<const float4*>(tokrow + ac);
  float4 tv1 = *reinterpret_cast<const float4*>(tokrow + ac + 4);
  float4 pv0 = *reinterpret_cast<const float4*>(posrow + ac);
  float4 pv1 = *reinterpret_cast<const float4*>(posrow + ac + 4);
  u16x8 q0 = *reinterpret_cast<const u16x8*>(bqrow + bc);
  u16x8 q1 = *reinterpret_cast<const u16x8*>(bqrow + bc + 8);
  u16x8 v0 = *reinterpret_cast<const u16x8*>(bvrow + bc);
  u16x8 v1 = *reinterpret_cast<const u16x8*>(bvrow + bc + 8);

  for (int k0 = 0; k0 < kDim; k0 += 32) {
    unsigned short av[8];
    av[0]=f2bf(tv0.x+pv0.x); av[1]=f2bf(tv0.y+pv0.y); av[2]=f2bf(tv0.z+pv0.z); av[3]=f2bf(tv0.w+pv0.w);
    av[4]=f2bf(tv1.x+pv1.x); av[5]=f2bf(tv1.y+pv1.y); av[6]=f2bf(tv1.z+pv1.z); av[7]=f2bf(tv1.w+pv1.w);
    *reinterpret_cast<u16x8*>(&As[ar][ac]) = *reinterpret_cast<u16x8*>(&av[0]);
    *reinterpret_cast<u16x8*>(&Bq[br][bc])     = q0;
    *reinterpret_cast<u16x8*>(&Bq[br][bc + 8]) = q1;
    *reinterpret_cast<u16x8*>(&Bv[br][bc])     = v0;
    *reinterpret_cast<u16x8*>(&Bv[br][bc + 8]) = v1;
    __syncthreads();
    if (k0 + 32 < kDim) {
      const int kn = k0 + 32;
      tv0 = *reinterpret_cast<const float4*>(tokrow + kn + ac);
      tv1 = *reinterpret_cast<const float4*>(tokrow + kn + ac + 4);
      pv0 = *reinterpret_cast<const float4*>(posrow + kn + ac);
      pv1 = *reinterpret_cast<const float4*>(posrow + kn + ac + 4);
      q0 = *reinterpret_cast<const u16x8*>(bqrow + kn + bc);
      q1 = *reinterpret_cast<const u16x8*>(bqrow + kn + bc + 8);
      v0 = *reinterpret_cast<const u16x8*>(bvrow + kn + bc);
      v1 = *reinterpret_cast<const u16x8*>(bvrow + kn + bc + 8);
    }
    bf16x8 a[4], bq[2], bv[2];
    #pragma unroll
    for (int mt = 0; mt < 4; ++mt) a[mt] = *reinterpret_cast<const bf16x8*>(&As[mt*16 + fr][kg]);
    #pragma unroll
    for (int nt = 0; nt < 2; ++nt) {
      bq[nt] = *reinterpret_cast<const bf16x8*>(&Bq[wave*32 + nt*16 + fr][kg]);
      bv[nt] = *reinterpret_cast<const bf16x8*>(&Bv[wave*32 + nt*16 + fr][kg]);
    }
    #pragma unroll
    for (int mt = 0; mt < 4; ++mt)
      #pragma unroll
      for (int nt = 0; nt < 2; ++nt) {
        accq[mt][nt] = __builtin_amdgcn_mfma_f32_16x16x32_bf16(a[mt], bq[nt], accq[mt][nt], 0, 0, 0);
        accv[mt][nt] = __builtin_amdgcn_mfma_f32_16x16x32_bf16(a[mt], bv[nt], accv[mt][nt], 0, 0, 0);
      }
    __syncthreads();
  }
  const int b = m0 >> 9;
  unsigned short* vb = VtT + (size_t)b * kDim * kTok;
  #pragma unroll
  for (int mt = 0; mt < 4; ++mt) {
    const int trow = m0 + mt*16 + crow;
    const int tloc = trow & (kTok - 1);
    #pragma unroll
    for (int nt = 0; nt < 2; ++nt) {
      const int dcol = n0 + wave*32 + nt*16 + fr;
      u16x4 pk;
      #pragma unroll
      for (int r = 0; r < 4; ++r) {
        Qk[(size_t)(trow + r) * kDim + dcol] = f2bf(accq[mt][nt][r]);
        pk[r] = f2bf(accv[mt][nt][r]);
      }
      *reinterpret_cast<u16x4*>(vb + (size_t)dcol * kTok + tloc) = pk;
    }
  }
}

// ---------------- scores = Qk@Mb^T -> masked softmax -> Wt[b][s][t] ------------
// wave-per-block, 32 t x 64 s, grid (16, 32)
__global__ __launch_bounds__(64) void k_scores(
    const unsigned short* __restrict__ Qk, const unsigned short* __restrict__ Mb,
    const int* __restrict__ mask, const float* __restrict__ vf,
    unsigned short* __restrict__ Wt)
{
  __shared__ unsigned short As[32][kPad];
  __shared__ unsigned short Bs[64][kPad];
  const int lane = threadIdx.x;
  const int b = blockIdx.y, t0 = blockIdx.x * 32;
  const int fr = lane & 15, kg = (lane >> 4) << 3, crow = (lane >> 4) << 2;
  const int ar = lane >> 1, ac = (lane & 1) << 4;
  f32x4 acc[2][4];
  #pragma unroll
  for (int i = 0; i < 2; ++i)
    #pragma unroll
    for (int j = 0; j < 4; ++j) acc[i][j] = (f32x4)(0.f);
  const unsigned short* qrow = Qk + (size_t)(b*kTok + t0 + ar) * kDim;
  const unsigned short* krow = Mb + (size_t)(b*kSlots + lane) * kDim;

  u16x8 pa0 = *reinterpret_cast<const u16x8*>(qrow + ac);
  u16x8 pa1 = *reinterpret_cast<const u16x8*>(qrow + ac + 8);
  u16x8 pb[4];
  #pragma unroll
  for (int h = 0; h < 4; ++h) pb[h] = *reinterpret_cast<const u16x8*>(krow + 8*h);

  for (int k0 = 0; k0 < kDim; k0 += 32) {
    *reinterpret_cast<u16x8*>(&As[ar][ac])     = pa0;
    *reinterpret_cast<u16x8*>(&As[ar][ac + 8]) = pa1;
    #pragma unroll
    for (int h = 0; h < 4; ++h) *reinterpret_cast<u16x8*>(&Bs[lane][8*h]) = pb[h];
    __syncthreads();
    if (k0 + 32 < kDim) {
      const int kn = k0 + 32;
      pa0 = *reinterpret_cast<const u16x8*>(qrow + kn + ac);
      pa1 = *reinterpret_cast<const u16x8*>(qrow + kn + ac + 8);
      #pragma unroll
      for (int h = 0; h < 4; ++h) pb[h] = *reinterpret_cast<const u16x8*>(krow + kn + 8*h);
    }
    bf16x8 a[2], bb[4];
    #pragma unroll
    for (int mt = 0; mt < 2; ++mt) a[mt] = *reinterpret_cast<const bf16x8*>(&As[mt*16 + fr][kg]);
    #pragma unroll
    for (int nt = 0; nt < 4; ++nt) bb[nt] = *reinterpret_cast<const bf16x8*>(&Bs[nt*16 + fr][kg]);
    #pragma unroll
    for (int mt = 0; mt < 2; ++mt)
      #pragma unroll
      for (int nt = 0; nt < 4; ++nt)
        acc[mt][nt] = __builtin_amdgcn_mfma_f32_16x16x32_bf16(a[mt], bb[nt], acc[mt][nt], 0, 0, 0);
    __syncthreads();
  }
  #pragma unroll
  for (int mt = 0; mt < 2; ++mt)
    #pragma unroll
    for (int nt = 0; nt < 4; ++nt)
      #pragma unroll
      for (int r = 0; r < 4; ++r)
        acc[mt][nt][r] = clipf(acc[mt][nt][r] * kScale, 20.f);
  const float vfb = vf[b];
  float fac[2][4];
  #pragma unroll
  for (int mt = 0; mt < 2; ++mt) {
    #pragma unroll
    for (int r = 0; r < 4; ++r) {
      float mx = fmaxf(fmaxf(acc[mt][0][r], acc[mt][1][r]), fmaxf(acc[mt][2][r], acc[mt][3][r]));
      #pragma unroll
      for (int m = 1; m < 16; m <<= 1) mx = fmaxf(mx, __shfl_xor(mx, m, 64));
      float sum = 0.f;
      #pragma unroll
      for (int nt = 0; nt < 4; ++nt) { float e = __expf(acc[mt][nt][r] - mx); acc[mt][nt][r] = e; sum += e; }
      #pragma unroll
      for (int m = 1; m < 16; m <<= 1) sum += __shfl_xor(sum, m, 64);
      const int tloc = t0 + mt*16 + crow + r;
      const bool keep = (mask[b*kTok + tloc] > 0) || (vfb == 0.f);
      fac[mt][r] = keep ? (1.f / sum) : 0.f;
    }
  }
  unsigned short* wb = Wt + (size_t)b * kSlots * kTok;
  #pragma unroll
  for (int mt = 0; mt < 2; ++mt) {
    const int tbase = t0 + mt*16 + crow;
    #pragma unroll
    for (int nt = 0; nt < 4; ++nt) {
      const int s = nt*16 + fr;
      u16x4 pk;
      #pragma unroll
      for (int r = 0; r < 4; ++r) pk[r] = f2bf(acc[mt][nt][r] * fac[mt][r]);
      *reinterpret_cast<u16x4*>(wb + (size_t)s * kTok + tbase) = pk;
    }
  }
}

// ---------------- write = Wt@VtT^T (K=512), gate = sigmoid(Mb@gWT^T+gb) (K=768),
//                  M' = clip(0.9M + 0.1 g*write); M f32 + MbOut bf16 -----------
// wave-per-block, 64 s x 64 d, grid (12, 32)
__global__ __launch_bounds__(64) void k_write_gate(
    const unsigned short* __restrict__ Wt, const unsigned short* __restrict__ VtT,
    const unsigned short* __restrict__ MbIn, const unsigned short* __restrict__ gWT,
    const float* __restrict__ gb, float* __restrict__ M, unsigned short* __restrict__ MbOut)
{
  __shared__ unsigned short As[64][kPad];
  __shared__ unsigned short Bs[64][kPad];
  const int lane = threadIdx.x;
  const int b = blockIdx.y, n0 = blockIdx.x * 64;
  const int fr = lane & 15, kg = (lane >> 4) << 3, crow = (lane >> 4) << 2;
  f32x4 aw[4][4], ag[4][4];
  #pragma unroll
  for (int i = 0; i < 4; ++i)
    #pragma unroll
    for (int j = 0; j < 4; ++j) { aw[i][j] = (f32x4)(0.f); ag[i][j] = (f32x4)(0.f); }

  // ---- phase 1: write accumulation, K = 512 (t) ----
  {
    const unsigned short* arow = Wt  + (size_t)b * kSlots * kTok + (size_t)lane * kTok;
    const unsigned short* brow = VtT + (size_t)b * kDim * kTok + (size_t)(n0 + lane) * kTok;
    u16x8 pa[4], pb[4];
    #pragma unroll
    for (int h = 0; h < 4; ++h) {
      pa[h] = *reinterpret_cast<const u16x8*>(arow + 8*h);
      pb[h] = *reinterpret_cast<const u16x8*>(brow + 8*h);
    }
    for (int k0 = 0; k0 < kTok; k0 += 32) {
      #pragma unroll
      for (int h = 0; h < 4; ++h) {
        *reinterpret_cast<u16x8*>(&As[lane][8*h]) = pa[h];
        *reinterpret_cast<u16x8*>(&Bs[lane][8*h]) = pb[h];
      }
      __syncthreads();
      if (k0 + 32 < kTok) {
        const int kn = k0 + 32;
        #pragma unroll
        for (int h = 0; h < 4; ++h) {
          pa[h] = *reinterpret_cast<const u16x8*>(arow + kn + 8*h);
          pb[h] = *reinterpret_cast<const u16x8*>(brow + kn + 8*h);
        }
      }
      bf16x8 a[4], bb[4];
      #pragma unroll
      for (int mt = 0; mt < 4; ++mt) a[mt] = *reinterpret_cast<const bf16x8*>(&As[mt*16 + fr][kg]);
      #pragma unroll
      for (int nt = 0; nt < 4; ++nt) bb[nt] = *reinterpret_cast<const bf16x8*>(&Bs[nt*16 + fr][kg]);
      #pragma unroll
      for (int mt = 0; mt < 4; ++mt)
        #pragma unroll
        for (int nt = 0; nt < 4; ++nt)
          aw[mt][nt] = __builtin_amdgcn_mfma_f32_16x16x32_bf16(a[mt], bb[nt], aw[mt][nt], 0, 0, 0);
      __syncthreads();
    }
  }
  // ---- phase 2: gate accumulation, K = 768 (d) ----
  {
    const unsigned short* arow = MbIn + (size_t)(b * kSlots + lane) * kDim;
    const unsigned short* brow = gWT + (size_t)(n0 + lane) * kDim;
    u16x8 pa[4], pb[4];
    #pragma unroll
    for (int h = 0; h < 4; ++h) {
      pa[h] = *reinterpret_cast<const u16x8*>(arow + 8*h);
      pb[h] = *reinterpret_cast<const u16x8*>(brow + 8*h);
    }
    for (int k0 = 0; k0 < kDim; k0 += 32) {
      #pragma unroll
      for (int h = 0; h < 4; ++h) {
        *reinterpret_cast<u16x8*>(&As[lane][8*h]) = pa[h];
        *reinterpret_cast<u16x8*>(&Bs[lane][8*h]) = pb[h];
      }
      __syncthreads();
      if (k0 + 32 < kDim) {
        const int kn = k0 + 32;
        #pragma unroll
        for (int h = 0; h < 4; ++h) {
          pa[h] = *reinterpret_cast<const u16x8*>(arow + kn + 8*h);
          pb[h] = *reinterpret_cast<const u16x8*>(brow + kn + 8*h);
        }
      }
      bf16x8 a[4], bb[4];
      #pragma unroll
      for (int mt = 0; mt < 4; ++mt) a[mt] = *reinterpret_cast<const bf16x8*>(&As[mt*16 + fr][kg]);
      #pragma unroll
      for (int nt = 0; nt < 4; ++nt) bb[nt] = *reinterpret_cast<const bf16x8*>(&Bs[nt*16 + fr][kg]);
      #pragma unroll
      for (int mt = 0; mt < 4; ++mt)
        #pragma unroll
        for (int nt = 0; nt < 4; ++nt)
          ag[mt][nt] = __builtin_amdgcn_mfma_f32_16x16x32_bf16(a[mt], bb[nt], ag[mt][nt], 0, 0, 0);
      __syncthreads();
    }
  }
  // ---- epilogue: M update ----
  #pragma unroll
  for (int mt = 0; mt < 4; ++mt) {
    const int s = mt*16 + crow;
    #pragma unroll
    for (int nt = 0; nt < 4; ++nt) {
      const int d = n0 + nt*16 + fr;
      #pragma unroll
      for (int r = 0; r < 4; ++r) {
        const size_t off = (size_t)(b*kSlots + s + r) * kDim + d;
        float z = ag[mt][nt][r] + gb[d];
        float g = 1.f / (1.f + __expf(-z));
        float mn = clipf(0.9f * M[off] + 0.1f * g * aw[mt][nt][r], 50.f);
        M[off] = mn;
        MbOut[off] = f2bf(mn);
      }
    }
  }
}

// ---------------- final pooling + LN + classifier ------------------------------
__global__ __launch_bounds__(256) void k_final(
    const unsigned short* __restrict__ Wt, const float* __restrict__ M,
    const int* __restrict__ mask, const float* __restrict__ vf,
    const float* __restrict__ lng, const float* __restrict__ lnb,
    const float* __restrict__ clsW, const float* __restrict__ clsb,
    float* __restrict__ out)
{
  __shared__ float red[256];
  __shared__ float wsum[kSlots];
  __shared__ float pooled[kDim];
  __shared__ float sh_mu, sh_var;
  const int b = blockIdx.x, tid = threadIdx.x;
  const unsigned short* wb = Wt + (size_t)b * kSlots * kTok;

  {
    const int s = tid & 63, q = tid >> 6;
    const unsigned short* wr = wb + (size_t)s * kTok + q * 128;
    const int* mrow = mask + b * kTok + q * 128;
    float p = 0.f;
    #pragma unroll 4
    for (int j = 0; j < 16; ++j) {
      u16x8 v = *reinterpret_cast<const u16x8*>(wr + 8*j);
      #pragma unroll
      for (int e = 0; e < 8; ++e)
        if (mrow[8*j + e] > 0) p += bf2f(v[e]);
    }
    red[tid] = p;
  }
  __syncthreads();
  if (tid < 64) wsum[tid] = red[tid] + red[tid+64] + red[tid+128] + red[tid+192];
  __syncthreads();

  const float denom = fmaxf(vf[b], 1.f);
  for (int d = tid; d < kDim; d += 256) {
    float acc = 0.f;
    const float* Mb2 = M + (size_t)(b*kSlots) * kDim + d;
    #pragma unroll 4
    for (int s = 0; s < kSlots; ++s) acc += wsum[s] * Mb2[(size_t)s * kDim];
    pooled[d] = acc / denom;
  }
  __syncthreads();

  float lp = 0.f;
  for (int d = tid; d < kDim; d += 256) lp += pooled[d];
  red[tid] = lp; __syncthreads();
  for (int off = 128; off > 0; off >>= 1) { if (tid < off) red[tid] += red[tid+off]; __syncthreads(); }
  if (tid == 0) sh_mu = red[0] / kDim;
  __syncthreads();
  const float mu = sh_mu;
  float lv = 0.f;
  for (int d = tid; d < kDim; d += 256) { float z = pooled[d] - mu; lv += z*z; }
  red[tid] = lv; __syncthreads();
  for (int off = 128; off > 0; off >>= 1) { if (tid < off) red[tid] += red[tid+off]; __syncthreads(); }
  if (tid == 0) sh_var = red[0] / kDim;
  __syncthreads();
  const float inv = rsqrtf(sh_var + 1e-5f);
  for (int d = tid; d < kDim; d += 256)
    pooled[d] = (pooled[d] - mu) * inv * lng[d] + lnb[d];
  __syncthreads();

  {
    const int c = tid & 7, dg = tid >> 3;
    float part = 0.f;
    for (int d = dg; d < kDim; d += 32) part += pooled[d] * clsW[(size_t)d * kCls + c];
    red[tid] = part;
  }
  __syncthreads();
  if (tid < 8) {
    float s = clsb[tid];
    #pragma unroll
    for (int dg = 0; dg < 32; ++dg) s += red[dg*8 + tid];
    if (!isfinite(s)) s = 0.f;
    out[b*kCls + tid] = s;
  }
}

}  // namespace

extern "C" void kernel_launch(void* const* d_in, const int* in_sizes, int n_in,
                              void* d_out, int out_size, void* d_ws, size_t ws_size,
                              hipStream_t stream)
{
  const int*   ids = (const int*)  d_in[0];
  const int*   msk = (const int*)  d_in[1];
  const float* tok = (const float*)d_in[2];
  const float* pos = (const float*)d_in[3];
  const float* Wq  = (const float*)d_in[4];
  const float* Wk  = (const float*)d_in[5];
  const float* Wv  = (const float*)d_in[6];
  const float* gW  = (const float*)d_in[7];
  const float* gb  = (const float*)d_in[8];
  const float* lng = (const float*)d_in[9];
  const float* lnb = (const float*)d_in[10];
  const float* cW  = (const float*)d_in[11];
  const float* cb  = (const float*)d_in[12];
  const float* mi  = (const float*)d_in[13];
  float* out = (float*)d_out;
  char* base = (char*)d_ws;

  size_t off = 0;
  unsigned short* Qk   = (unsigned short*)(base + off); off += (size_t)kBatch*kTok*kDim*2;    // 25.2 MB
  unsigned short* VtT  = (unsigned short*)(base + off); off += (size_t)kBatch*kDim*kTok*2;    // 25.2 MB
  unsigned short* Wt   = (unsigned short*)(base + off); off += (size_t)kBatch*kSlots*kTok*2;  // 2.1 MB
  unsigned short* WvT  = (unsigned short*)(base + off); off += (size_t)kDim*kDim*2;
  unsigned short* gWT  = (unsigned short*)(base + off); off += (size_t)kDim*kDim*2;
  unsigned short* WqkT = (unsigned short*)(base + off); off += (size_t)kDim*kDim*2;
  float* M   = (float*)(base + off);          off += (size_t)kBatch*kSlots*kDim*4;            // 6.3 MB
  unsigned short* Mb0 = (unsigned short*)(base + off); off += (size_t)kBatch*kSlots*kDim*2;   // 3.1 MB
  unsigned short* Mb1 = (unsigned short*)(base + off); off += (size_t)kBatch*kSlots*kDim*2;   // 3.1 MB
  float* vf  = (float*)(base + off);          off += 256;

  k_prep<<<dim3(kDim/32, kDim/32, 2), 256, 0, stream>>>(Wv, gW, WvT, gWT);
  k_wqk<<<dim3(kDim/64, kDim/64), 64, 0, stream>>>(Wk, Wq, WqkT);
  k_minit<<<dim3((kBatch*kSlots*kDim/4)/256), 256, 0, stream>>>(mi, M, Mb0);
  k_valid<<<dim3(kBatch), 256, 0, stream>>>(msk, vf);
  k_embed_qv<<<dim3(kBatch*kTok/64, kDim/128), 256, 0, stream>>>(ids, tok, pos, WqkT, WvT, Qk, VtT);
  unsigned short* mcur = Mb0;
  unsigned short* mnext = Mb1;
  for (int it = 0; it < kSteps; ++it) {
    k_scores<<<dim3(kTok/32, kBatch), 64, 0, stream>>>(Qk, mcur, msk, vf, Wt);
    k_write_gate<<<dim3(kDim/64, kBatch), 64, 0, stream>>>(Wt, VtT, mcur, gWT, gb, M, mnext);
    unsigned short* t = mcur; mcur = mnext; mnext = t;
  }
  k_scores<<<dim3(kTok/32, kBatch), 64, 0, stream>>>(Qk, mcur, msk, vf, Wt);
  k_final<<<dim3(kBatch), 256, 0, stream>>>(Wt, M, msk, vf, lng, lnb, cW, cb, out);

  (void)in_sizes; (void)n_in; (void)out_size; (void)ws_size;
}